// Round 1
// baseline (1803.595 us; speedup 1.0000x reference)
//
#include <hip/hip_runtime.h>
#include <hip/hip_bf16.h>

// ---------------------------------------------------------------------------
// Sparse conv backbone, fp32 baseline.
// sparse_conv(feats, W, in_map): out[j] = sum_k fpad[in_map[k][j]] @ W[k]
//   (out_map is identity-or-sentinel, so no scatter atomics are needed;
//    invalid taps gather the zero pad row at index n_in)
// ---------------------------------------------------------------------------

#define BN_EPS 1e-5f

static inline int ceil_div(int a, int b) { return (a + b - 1) / b; }

// Build x0 = concat(x_geo, x_col) -> (n_vox, 4)
__global__ void build_x0_kernel(const float* __restrict__ geo,
                                const float* __restrict__ col,
                                float* __restrict__ x0, int n) {
    int j = blockIdx.x * blockDim.x + threadIdx.x;
    if (j >= n) return;
    float4 v;
    v.x = geo[j];
    v.y = col[j * 3 + 0];
    v.z = col[j * 3 + 1];
    v.w = col[j * 3 + 2];
    ((float4*)x0)[j] = v;
}

// Generic gather-GEMM sparse conv.
// fpad: (n_in+1, CIN) with row n_in == 0.  W: (K, CIN, COUT).
// in_map: (K, n_out).  out: (n_out, COUT) region of a padded buffer.
template <int CIN, int COUT, int ROWS>
__global__ __launch_bounds__(256) void conv_kernel(
    const float* __restrict__ fpad, const float* __restrict__ W,
    const int* __restrict__ in_map, float* __restrict__ out,
    int n_out, int n_in, int K, int do_relu) {
    __shared__ float lds_f[ROWS][CIN];
    __shared__ float lds_w[CIN][COUT];
    constexpr int G = 256 / COUT;   // row groups per block
    constexpr int RPT = ROWS / G;   // rows per thread
    constexpr int WN = CIN * COUT;
    constexpr int F4 = CIN / 4;     // float4 per feature row
    constexpr int TOT4 = ROWS * F4;

    const int t = threadIdx.x;
    const int row0 = blockIdx.x * ROWS;
    const int c = t % COUT;
    const int g = t / COUT;

    float acc[RPT];
#pragma unroll
    for (int i = 0; i < RPT; ++i) acc[i] = 0.f;

    for (int k = 0; k < K; ++k) {
        // stage weights for this offset
        const float* wk = W + (size_t)k * WN;
#pragma unroll
        for (int e = t; e < WN; e += 256) ((float*)lds_w)[e] = wk[e];
        // gather feature rows for this offset
        const int* mk = in_map + (size_t)k * n_out;
        for (int e = t; e < TOT4; e += 256) {
            int r = e / F4, comp = e % F4;
            int j = row0 + r;
            int idx = (j < n_out) ? mk[j] : n_in;
            float4 v = ((const float4*)(fpad + (size_t)idx * CIN))[comp];
            ((float4*)&lds_f[r][0])[comp] = v;
        }
        __syncthreads();
#pragma unroll
        for (int i = 0; i < RPT; ++i) {
            int r = g + i * G;
            float a = 0.f;
#pragma unroll
            for (int ci = 0; ci < CIN; ++ci) a += lds_f[r][ci] * lds_w[ci][c];
            acc[i] += a;
        }
        __syncthreads();
    }
#pragma unroll
    for (int i = 0; i < RPT; ++i) {
        int r = row0 + g + i * G;
        if (r < n_out) {
            float v = acc[i];
            if (do_relu) v = fmaxf(v, 0.f);
            out[(size_t)r * COUT + c] = v;
        }
    }
}

// Per-channel sum / sumsq partial reduction -> atomicAdd into stats[2][C]
template <int C>
__global__ __launch_bounds__(256) void bn_stats_kernel(
    const float* __restrict__ x, int n, float* __restrict__ stats) {
    constexpr int G = 256 / C;
    const int t = threadIdx.x, c = t % C, g = t / C;
    float s = 0.f, s2 = 0.f;
    const int stride = gridDim.x * G;
    for (int r = blockIdx.x * G + g; r < n; r += stride) {
        float v = x[(size_t)r * C + c];
        s += v;
        s2 += v * v;
    }
    __shared__ float ls[2][256];
    ls[0][t] = s;
    ls[1][t] = s2;
    __syncthreads();
#pragma unroll
    for (int h = G / 2; h > 0; h >>= 1) {
        if (g < h) {
            ls[0][t] += ls[0][t + h * C];
            ls[1][t] += ls[1][t + h * C];
        }
        __syncthreads();
    }
    if (g == 0) {
        atomicAdd(&stats[c], ls[0][t]);
        atomicAdd(&stats[C + c], ls[1][t]);
    }
}

// y = relu(bn(x)) in place
template <int C>
__global__ void bn_apply_relu_kernel(float* __restrict__ x,
                                     const float* __restrict__ stats,
                                     const float* __restrict__ gamma,
                                     const float* __restrict__ beta, int n) {
    int i = blockIdx.x * blockDim.x + threadIdx.x;
    if (i >= n * C) return;
    int c = i % C;
    float rn = 1.f / (float)n;
    float mu = stats[c] * rn;
    float var = stats[C + c] * rn - mu * mu;
    float inv = rsqrtf(var + BN_EPS);
    float v = (x[i] - mu) * inv * gamma[c] + beta[c];
    x[i] = fmaxf(v, 0.f);
}

// out = relu(bn(y) + res)
template <int C>
__global__ void bn_apply_res_relu_kernel(const float* __restrict__ y,
                                         const float* __restrict__ res,
                                         const float* __restrict__ stats,
                                         const float* __restrict__ gamma,
                                         const float* __restrict__ beta,
                                         float* __restrict__ out, int n) {
    int i = blockIdx.x * blockDim.x + threadIdx.x;
    if (i >= n * C) return;
    int c = i % C;
    float rn = 1.f / (float)n;
    float mu = stats[c] * rn;
    float var = stats[C + c] * rn - mu * mu;
    float inv = rsqrtf(var + BN_EPS);
    float v = (y[i] - mu) * inv * gamma[c] + beta[c] + res[i];
    out[i] = fmaxf(v, 0.f);
}

extern "C" void kernel_launch(void* const* d_in, const int* in_sizes, int n_in_cnt,
                              void* d_out, int out_size, void* d_ws, size_t ws_size,
                              hipStream_t stream) {
    const float* x_geo = (const float*)d_in[0];
    const float* x_col = (const float*)d_in[1];
    const float* w0    = (const float*)d_in[2];   // (125,4,32)
    const float* w_e1  = (const float*)d_in[3];   // (2,2,27,32,32)
    const float* g_e1  = (const float*)d_in[4];   // (2,2,32)
    const float* b_e1  = (const float*)d_in[5];
    const float* w2    = (const float*)d_in[6];   // (27,32,64)
    const float* w_e2  = (const float*)d_in[7];   // (2,2,27,64,64)
    const float* g_e2  = (const float*)d_in[8];   // (2,2,64)
    const float* b_e2  = (const float*)d_in[9];
    const int* m1_in = (const int*)d_in[10];
    const int* m2_in = (const int*)d_in[12];
    const int* m3_in = (const int*)d_in[14];
    const int* m4_in = (const int*)d_in[16];

    const int n_vox = in_sizes[0];
    const int nc2 = in_sizes[10] / 125;
    const int nc4 = in_sizes[14] / 27;
    (void)out_size; (void)ws_size; (void)n_in_cnt;

    // workspace layout (floats)
    float* ws = (float*)d_ws;
    float* stats = ws;                     // 8 slots x 128 floats
    float* x0 = stats + 8 * 128;           // (n_vox+1, 4)
    float* A  = x0 + (size_t)(n_vox + 1) * 4;   // (nc2+1, 32)
    float* B  = A + (size_t)(nc2 + 1) * 32;
    float* Cb = B + (size_t)(nc2 + 1) * 32;
    float* D  = Cb + (size_t)(nc2 + 1) * 32;    // (nc4+1, 64)
    float* E  = D + (size_t)(nc4 + 1) * 64;
    float* Fb = E + (size_t)(nc4 + 1) * 64;

    // zero: stats slots + pad rows of every conv-input buffer
    hipMemsetAsync(stats, 0, 8 * 128 * sizeof(float), stream);
    hipMemsetAsync(x0 + (size_t)n_vox * 4, 0, 4 * sizeof(float), stream);
    hipMemsetAsync(A + (size_t)nc2 * 32, 0, 32 * sizeof(float), stream);
    hipMemsetAsync(B + (size_t)nc2 * 32, 0, 32 * sizeof(float), stream);
    hipMemsetAsync(D + (size_t)nc4 * 64, 0, 64 * sizeof(float), stream);
    hipMemsetAsync(E + (size_t)nc4 * 64, 0, 64 * sizeof(float), stream);

    // stem: concat then k5s2 conv + relu
    build_x0_kernel<<<ceil_div(n_vox, 256), 256, 0, stream>>>(x_geo, x_col, x0, n_vox);
    conv_kernel<4, 32, 64><<<ceil_div(nc2, 64), 256, 0, stream>>>(
        x0, w0, m1_in, A, nc2, n_vox, 125, 1);

    const int F = 32;
    int slot = 0;
    // enc1: two BasicBlocks at 32ch on c2 coords
    for (int blk = 0; blk < 2; ++blk) {
        const float* wA = w_e1 + (size_t)(blk * 2 + 0) * 27 * F * F;
        const float* wB = w_e1 + (size_t)(blk * 2 + 1) * 27 * F * F;
        const float* gA = g_e1 + (blk * 2 + 0) * F; const float* bA = b_e1 + (blk * 2 + 0) * F;
        const float* gB = g_e1 + (blk * 2 + 1) * F; const float* bB = b_e1 + (blk * 2 + 1) * F;

        conv_kernel<32, 32, 64><<<ceil_div(nc2, 64), 256, 0, stream>>>(
            A, wA, m2_in, B, nc2, nc2, 27, 0);
        bn_stats_kernel<32><<<256, 256, 0, stream>>>(B, nc2, stats + slot * 128);
        bn_apply_relu_kernel<32><<<ceil_div(nc2 * 32, 256), 256, 0, stream>>>(
            B, stats + slot * 128, gA, bA, nc2);
        ++slot;
        conv_kernel<32, 32, 64><<<ceil_div(nc2, 64), 256, 0, stream>>>(
            B, wB, m2_in, Cb, nc2, nc2, 27, 0);
        bn_stats_kernel<32><<<256, 256, 0, stream>>>(Cb, nc2, stats + slot * 128);
        bn_apply_res_relu_kernel<32><<<ceil_div(nc2 * 32, 256), 256, 0, stream>>>(
            Cb, A, stats + slot * 128, gB, bB, A, nc2);
        ++slot;
    }

    // conv2: 32ch@c2 -> 64ch@c4 (no BN/relu)
    conv_kernel<32, 64, 32><<<ceil_div(nc4, 32), 256, 0, stream>>>(
        A, w2, m3_in, D, nc4, nc2, 27, 0);

    const int F2 = 64;
    // enc2: two BasicBlocks at 64ch on c4 coords
    for (int blk = 0; blk < 2; ++blk) {
        const float* wA = w_e2 + (size_t)(blk * 2 + 0) * 27 * F2 * F2;
        const float* wB = w_e2 + (size_t)(blk * 2 + 1) * 27 * F2 * F2;
        const float* gA = g_e2 + (blk * 2 + 0) * F2; const float* bA = b_e2 + (blk * 2 + 0) * F2;
        const float* gB = g_e2 + (blk * 2 + 1) * F2; const float* bB = b_e2 + (blk * 2 + 1) * F2;
        float* res_out = (blk == 1) ? (float*)d_out : D;

        conv_kernel<64, 64, 32><<<ceil_div(nc4, 32), 256, 0, stream>>>(
            D, wA, m4_in, E, nc4, nc4, 27, 0);
        bn_stats_kernel<64><<<256, 256, 0, stream>>>(E, nc4, stats + slot * 128);
        bn_apply_relu_kernel<64><<<ceil_div(nc4 * 64, 256), 256, 0, stream>>>(
            E, stats + slot * 128, gA, bA, nc4);
        ++slot;
        conv_kernel<64, 64, 32><<<ceil_div(nc4, 32), 256, 0, stream>>>(
            E, wB, m4_in, Fb, nc4, nc4, 27, 0);
        bn_stats_kernel<64><<<256, 256, 0, stream>>>(Fb, nc4, stats + slot * 128);
        bn_apply_res_relu_kernel<64><<<ceil_div(nc4 * 64, 256), 256, 0, stream>>>(
            Fb, D, stats + slot * 128, gB, bB, res_out, nc4);
        ++slot;
    }
}

// Round 2
// 470.733 us; speedup vs baseline: 3.8315x; 3.8315x over previous
//
#include <hip/hip_runtime.h>
#include <hip/hip_bf16.h>

// ---------------------------------------------------------------------------
// Sparse conv backbone, bf16 MFMA version.
// sparse_conv: out[j] = sum_k fpad[in_map[k][j]] @ W[k]  (identity scatter,
// sentinel gathers zero pad row).  GEMM view: M=n_out, N=COUT, Kdim=K*CIN.
// MFMA 16x16x32 bf16:
//   A-frag: lane holds A[m=lane&15][kd=quad*8+j], j=0..7 (16B contiguous)
//   B-frag: lane holds B[kd=quad*8+j][n=lane&15]  (pre-packed weights)
//   C/D   : col=lane&15, row=quad*4+reg
// ---------------------------------------------------------------------------

typedef float f4 __attribute__((ext_vector_type(4)));
typedef short short8 __attribute__((ext_vector_type(8)));
typedef short short4v __attribute__((ext_vector_type(4)));

#define BN_EPS 1e-5f

static inline int ceil_div(int a, int b) { return (a + b - 1) / b; }

// ---------------- weight packing ----------------
// Wf element e (within segment): j=e&7, lane=(e>>3)&63, rest=e>>9,
// ntile=rest%NT, chunk=rest/NT, kd=chunk*32+(lane>>4)*8+j,
// value = W[kd/CIN][kd%CIN][ntile*16+(lane&15)], 0 if kd/CIN >= K.
struct Seg {
    const float* W;
    long long begin, end;
    int K, CIN, COUT;
};
struct PackArgs { Seg s[10]; };

__global__ __launch_bounds__(256) void pack_all(PackArgs pa, __hip_bfloat16* Wf,
                                                long long total) {
    long long e = (long long)blockIdx.x * 256 + threadIdx.x;
    if (e >= total) return;
    int si = 0;
#pragma unroll
    for (int i = 0; i < 10; ++i)
        if (e >= pa.s[i].end) si = i + 1;
    const Seg sg = pa.s[si];
    long long r = e - sg.begin;
    int j = (int)(r & 7);
    int lane = (int)((r >> 3) & 63);
    long long rest = r >> 9;
    int NT = sg.COUT >> 4;
    int ntile = (int)(rest % NT);
    int chunk = (int)(rest / NT);
    int kd = chunk * 32 + ((lane >> 4) << 3) + j;
    int koff = kd / sg.CIN;
    int ci = kd % sg.CIN;
    int n = ntile * 16 + (lane & 15);
    float v = (koff < sg.K) ? sg.W[((size_t)koff * sg.CIN + ci) * sg.COUT + n] : 0.f;
    Wf[e] = __float2bfloat16(v);
}

// ---------------- stem input build ----------------
__global__ void build_x0(const float* __restrict__ geo, const float* __restrict__ col,
                         __hip_bfloat16* __restrict__ x0, int n) {
    int j = blockIdx.x * blockDim.x + threadIdx.x;
    if (j >= n) return;
    x0[j * 4 + 0] = __float2bfloat16(geo[j]);
    x0[j * 4 + 1] = __float2bfloat16(col[j * 3 + 0]);
    x0[j * 4 + 2] = __float2bfloat16(col[j * 3 + 1]);
    x0[j * 4 + 3] = __float2bfloat16(col[j * 3 + 2]);
}

// ---------------- generic MFMA conv (CIN in {32,64}) ----------------
// Block = 256 threads = 4 waves. NT = COUT/16 column tiles; waves not used for
// columns handle extra row groups. Each wave: 2 M-tiles (32 rows) per group.
template <int CIN, int COUT, bool RELU>
__global__ __launch_bounds__(256) void conv_mfma(
    const __hip_bfloat16* __restrict__ feat,  // (n_in+1, CIN), pad row zero
    const __hip_bfloat16* __restrict__ Wf,    // packed frag layout
    const int* __restrict__ in_map,           // (K, n_out)
    __hip_bfloat16* __restrict__ out,         // (n_out[+1], COUT)
    float* __restrict__ stats,                // [4][2][COUT] or null
    int n_out, int n_in, int K) {
    constexpr int NT = COUT / 16;
    constexpr int MG = 4 / NT;        // row groups per block
    constexpr int ROWS = MG * 32;
    constexpr int H = CIN / 32;
    const int t = threadIdx.x, w = t >> 6, lane = t & 63;
    const int quad = lane >> 4, ml = lane & 15;
    const int ntile = w & (NT - 1);
    const int mgroup = (NT == 4) ? 0 : (w >> 1);
    const int mb = blockIdx.x * ROWS + mgroup * 32;
    const int m0 = mb + ml, m1 = mb + 16 + ml;
    const bool v0 = m0 < n_out, v1 = m1 < n_out;

    f4 acc0 = {0.f, 0.f, 0.f, 0.f};
    f4 acc1 = {0.f, 0.f, 0.f, 0.f};

    for (int k = 0; k < K; ++k) {
        const int* mk = in_map + (size_t)k * n_out;
        int i0 = v0 ? mk[m0] : n_in;
        int i1 = v1 ? mk[m1] : n_in;
        const __hip_bfloat16* f0 = feat + (size_t)i0 * CIN + quad * 8;
        const __hip_bfloat16* f1 = feat + (size_t)i1 * CIN + quad * 8;
#pragma unroll
        for (int h = 0; h < H; ++h) {
            int chunk = k * H + h;
            short8 b = *(const short8*)(Wf + ((size_t)(chunk * NT + ntile) * 64 + lane) * 8);
            short8 a0 = *(const short8*)(f0 + h * 32);
            short8 a1 = *(const short8*)(f1 + h * 32);
            acc0 = __builtin_amdgcn_mfma_f32_16x16x32_bf16(a0, b, acc0, 0, 0, 0);
            acc1 = __builtin_amdgcn_mfma_f32_16x16x32_bf16(a1, b, acc1, 0, 0, 0);
        }
    }

    const int col = ntile * 16 + ml;
    float s = 0.f, s2 = 0.f;
#pragma unroll
    for (int i = 0; i < 4; ++i) {
        int r0 = mb + quad * 4 + i;
        if (r0 < n_out) {
            float v = acc0[i];
            if (RELU) v = fmaxf(v, 0.f);
            out[(size_t)r0 * COUT + col] = __float2bfloat16(v);
            s += v; s2 += v * v;
        }
        int r1 = mb + 16 + quad * 4 + i;
        if (r1 < n_out) {
            float v = acc1[i];
            if (RELU) v = fmaxf(v, 0.f);
            out[(size_t)r1 * COUT + col] = __float2bfloat16(v);
            s += v; s2 += v * v;
        }
    }
    if (stats) {
        s += __shfl_xor(s, 16);  s += __shfl_xor(s, 32);
        s2 += __shfl_xor(s2, 16); s2 += __shfl_xor(s2, 32);
        if (quad == 0) {
            int sub = blockIdx.x & 3;
            atomicAdd(&stats[(sub * 2 + 0) * COUT + col], s);
            atomicAdd(&stats[(sub * 2 + 1) * COUT + col], s2);
        }
    }
}

// ---------------- stem conv (CIN=4, COUT=32, K=125, relu) ----------------
__global__ __launch_bounds__(256) void stem_mfma(
    const __hip_bfloat16* __restrict__ feat,  // (n_in+1, 4), pad row zero
    const __hip_bfloat16* __restrict__ Wf,    // 16 chunks, NT=2 (padded K)
    const int* __restrict__ in_map,           // (125, n_out)
    __hip_bfloat16* __restrict__ out,         // (n_out[+1], 32)
    int n_out, int n_in) {
    const int t = threadIdx.x, w = t >> 6, lane = t & 63;
    const int quad = lane >> 4, ml = lane & 15;
    const int ntile = w & 1, mgroup = w >> 1;
    const int mb = blockIdx.x * 64 + mgroup * 32;
    const int m0 = mb + ml, m1 = mb + 16 + ml;
    const bool v0 = m0 < n_out, v1 = m1 < n_out;

    f4 acc0 = {0.f, 0.f, 0.f, 0.f};
    f4 acc1 = {0.f, 0.f, 0.f, 0.f};

    for (int chunk = 0; chunk < 16; ++chunk) {
        int k0 = chunk * 8 + quad * 2;
        int k1 = k0 + 1;
        short8 b = *(const short8*)(Wf + ((size_t)(chunk * 2 + ntile) * 64 + lane) * 8);
        int ia = (v0 && k0 < 125) ? in_map[(size_t)k0 * n_out + m0] : n_in;
        int ib = (v0 && k1 < 125) ? in_map[(size_t)k1 * n_out + m0] : n_in;
        int ic = (v1 && k0 < 125) ? in_map[(size_t)k0 * n_out + m1] : n_in;
        int id = (v1 && k1 < 125) ? in_map[(size_t)k1 * n_out + m1] : n_in;
        short4v pa = *(const short4v*)(feat + (size_t)ia * 4);
        short4v pb = *(const short4v*)(feat + (size_t)ib * 4);
        short4v pc = *(const short4v*)(feat + (size_t)ic * 4);
        short4v pd = *(const short4v*)(feat + (size_t)id * 4);
        short8 a0, a1;
        a0[0] = pa[0]; a0[1] = pa[1]; a0[2] = pa[2]; a0[3] = pa[3];
        a0[4] = pb[0]; a0[5] = pb[1]; a0[6] = pb[2]; a0[7] = pb[3];
        a1[0] = pc[0]; a1[1] = pc[1]; a1[2] = pc[2]; a1[3] = pc[3];
        a1[4] = pd[0]; a1[5] = pd[1]; a1[6] = pd[2]; a1[7] = pd[3];
        acc0 = __builtin_amdgcn_mfma_f32_16x16x32_bf16(a0, b, acc0, 0, 0, 0);
        acc1 = __builtin_amdgcn_mfma_f32_16x16x32_bf16(a1, b, acc1, 0, 0, 0);
    }

    const int col = ntile * 16 + ml;
#pragma unroll
    for (int i = 0; i < 4; ++i) {
        int r0 = mb + quad * 4 + i;
        if (r0 < n_out)
            out[(size_t)r0 * 32 + col] = __float2bfloat16(fmaxf(acc0[i], 0.f));
        int r1 = mb + 16 + quad * 4 + i;
        if (r1 < n_out)
            out[(size_t)r1 * 32 + col] = __float2bfloat16(fmaxf(acc1[i], 0.f));
    }
}

// ---------------- BN apply variants ----------------
template <int C>
__device__ inline void bn_coef(const float* st, const float* g, const float* b,
                               int c, int n, float& sc, float& sh) {
    float rn = 1.f / (float)n;
    float sum = st[c] + st[2 * C + c] + st[4 * C + c] + st[6 * C + c];
    float sq  = st[C + c] + st[3 * C + c] + st[5 * C + c] + st[7 * C + c];
    float mu = sum * rn;
    float inv = rsqrtf(sq * rn - mu * mu + BN_EPS);
    sc = inv * g[c];
    sh = b[c] - mu * sc;
}

template <int C>
__global__ void bn_relu_kernel(__hip_bfloat16* __restrict__ x,
                               const float* __restrict__ st,
                               const float* __restrict__ g,
                               const float* __restrict__ b, int n) {
    int i = blockIdx.x * blockDim.x + threadIdx.x;
    if (i >= n * C) return;
    int c = i & (C - 1);
    float sc, sh;
    bn_coef<C>(st, g, b, c, n, sc, sh);
    float v = __bfloat162float(x[i]) * sc + sh;
    x[i] = __float2bfloat16(fmaxf(v, 0.f));
}

template <int C>
__global__ void bn_res_bf16_kernel(const __hip_bfloat16* __restrict__ y,
                                   const __hip_bfloat16* __restrict__ res,
                                   const float* __restrict__ st,
                                   const float* __restrict__ g,
                                   const float* __restrict__ b,
                                   __hip_bfloat16* __restrict__ out, int n) {
    int i = blockIdx.x * blockDim.x + threadIdx.x;
    if (i >= n * C) return;
    int c = i & (C - 1);
    float sc, sh;
    bn_coef<C>(st, g, b, c, n, sc, sh);
    float v = __bfloat162float(y[i]) * sc + sh + __bfloat162float(res[i]);
    out[i] = __float2bfloat16(fmaxf(v, 0.f));
}

template <int C>
__global__ void bn_res_f32_kernel(const __hip_bfloat16* __restrict__ y,
                                  const __hip_bfloat16* __restrict__ res,
                                  const float* __restrict__ st,
                                  const float* __restrict__ g,
                                  const float* __restrict__ b,
                                  float* __restrict__ out, int n) {
    int i = blockIdx.x * blockDim.x + threadIdx.x;
    if (i >= n * C) return;
    int c = i & (C - 1);
    float sc, sh;
    bn_coef<C>(st, g, b, c, n, sc, sh);
    float v = __bfloat162float(y[i]) * sc + sh + __bfloat162float(res[i]);
    out[i] = fmaxf(v, 0.f);
}

// ---------------------------------------------------------------------------
extern "C" void kernel_launch(void* const* d_in, const int* in_sizes, int n_in_cnt,
                              void* d_out, int out_size, void* d_ws, size_t ws_size,
                              hipStream_t stream) {
    const float* x_geo = (const float*)d_in[0];
    const float* x_col = (const float*)d_in[1];
    const float* w0    = (const float*)d_in[2];   // (125,4,32)
    const float* w_e1  = (const float*)d_in[3];   // (2,2,27,32,32)
    const float* g_e1  = (const float*)d_in[4];
    const float* b_e1  = (const float*)d_in[5];
    const float* w2    = (const float*)d_in[6];   // (27,32,64)
    const float* w_e2  = (const float*)d_in[7];   // (2,2,27,64,64)
    const float* g_e2  = (const float*)d_in[8];
    const float* b_e2  = (const float*)d_in[9];
    const int* m1_in = (const int*)d_in[10];
    const int* m2_in = (const int*)d_in[12];
    const int* m3_in = (const int*)d_in[14];
    const int* m4_in = (const int*)d_in[16];

    const int n_vox = in_sizes[0];
    const int nc2 = in_sizes[10] / 125;
    const int nc4 = in_sizes[14] / 27;
    (void)out_size; (void)ws_size; (void)n_in_cnt;

    // ---- carve workspace (256B-aligned chunks) ----
    char* p = (char*)d_ws;
    auto alloc = [&](size_t bytes) -> char* {
        char* r = p;
        p += (bytes + 255) & ~(size_t)255;
        return r;
    };
    float* stats = (float*)alloc(8 * 512 * sizeof(float));   // 8 slots x [4][2][64]
    __hip_bfloat16* x0 = (__hip_bfloat16*)alloc((size_t)(n_vox + 1) * 4 * 2);
    __hip_bfloat16* A  = (__hip_bfloat16*)alloc((size_t)(nc2 + 1) * 32 * 2);
    __hip_bfloat16* B  = (__hip_bfloat16*)alloc((size_t)(nc2 + 1) * 32 * 2);
    __hip_bfloat16* Cb = (__hip_bfloat16*)alloc((size_t)(nc2 + 1) * 32 * 2);
    __hip_bfloat16* D  = (__hip_bfloat16*)alloc((size_t)(nc4 + 1) * 64 * 2);
    __hip_bfloat16* E  = (__hip_bfloat16*)alloc((size_t)(nc4 + 1) * 64 * 2);
    __hip_bfloat16* Fb = (__hip_bfloat16*)alloc((size_t)(nc4 + 1) * 64 * 2);

    // packed weight segment sizes (elements)
    const long long sz_stem = 16LL * 2 * 512;   // 16 chunks (125*4 padded to 512)
    const long long sz_e1   = 27LL * 2 * 512;   // per enc1 conv
    const long long sz_c2   = 27LL * 4 * 512;
    const long long sz_e2   = 54LL * 4 * 512;   // per enc2 conv
    const long long wf_total = sz_stem + 4 * sz_e1 + sz_c2 + 4 * sz_e2;
    __hip_bfloat16* Wf = (__hip_bfloat16*)alloc((size_t)wf_total * 2);

    long long off_stem = 0;
    long long off_e1[4], off_e2[4];
    long long cur = sz_stem;
    for (int i = 0; i < 4; ++i) { off_e1[i] = cur; cur += sz_e1; }
    long long off_c2 = cur; cur += sz_c2;
    for (int i = 0; i < 4; ++i) { off_e2[i] = cur; cur += sz_e2; }

    // ---- zero stats + pad rows ----
    hipMemsetAsync(stats, 0, 8 * 512 * sizeof(float), stream);
    hipMemsetAsync(x0 + (size_t)n_vox * 4, 0, 4 * 2, stream);
    hipMemsetAsync(A + (size_t)nc2 * 32, 0, 32 * 2, stream);
    hipMemsetAsync(B + (size_t)nc2 * 32, 0, 32 * 2, stream);
    hipMemsetAsync(D + (size_t)nc4 * 64, 0, 64 * 2, stream);
    hipMemsetAsync(E + (size_t)nc4 * 64, 0, 64 * 2, stream);

    // ---- pack all weights ----
    PackArgs pa;
    cur = 0;
    auto seg = [&](int i, const float* W, int K, int CIN, int COUT, long long n) {
        pa.s[i].W = W; pa.s[i].K = K; pa.s[i].CIN = CIN; pa.s[i].COUT = COUT;
        pa.s[i].begin = cur; pa.s[i].end = cur + n; cur += n;
    };
    seg(0, w0, 125, 4, 32, sz_stem);
    for (int i = 0; i < 4; ++i)
        seg(1 + i, w_e1 + (size_t)i * 27 * 32 * 32, 27, 32, 32, sz_e1);
    seg(5, w2, 27, 32, 64, sz_c2);
    for (int i = 0; i < 4; ++i)
        seg(6 + i, w_e2 + (size_t)i * 27 * 64 * 64, 27, 64, 64, sz_e2);
    pack_all<<<ceil_div((int)wf_total, 256), 256, 0, stream>>>(pa, Wf, wf_total);

    // ---- stem ----
    build_x0<<<ceil_div(n_vox, 256), 256, 0, stream>>>(x_geo, x_col, x0, n_vox);
    stem_mfma<<<ceil_div(nc2, 64), 256, 0, stream>>>(x0, Wf + off_stem, m1_in, A,
                                                     nc2, n_vox);

    // ---- enc1: two BasicBlocks, 32ch on c2 ----
    int slot = 0;
    for (int blk = 0; blk < 2; ++blk) {
        const float* gA = g_e1 + (blk * 2 + 0) * 32, *bA = b_e1 + (blk * 2 + 0) * 32;
        const float* gB = g_e1 + (blk * 2 + 1) * 32, *bB = b_e1 + (blk * 2 + 1) * 32;
        conv_mfma<32, 32, false><<<ceil_div(nc2, 64), 256, 0, stream>>>(
            A, Wf + off_e1[blk * 2 + 0], m2_in, B, stats + slot * 512, nc2, nc2, 27);
        bn_relu_kernel<32><<<ceil_div(nc2 * 32, 256), 256, 0, stream>>>(
            B, stats + slot * 512, gA, bA, nc2);
        ++slot;
        conv_mfma<32, 32, false><<<ceil_div(nc2, 64), 256, 0, stream>>>(
            B, Wf + off_e1[blk * 2 + 1], m2_in, Cb, stats + slot * 512, nc2, nc2, 27);
        bn_res_bf16_kernel<32><<<ceil_div(nc2 * 32, 256), 256, 0, stream>>>(
            Cb, A, stats + slot * 512, gB, bB, A, nc2);
        ++slot;
    }

    // ---- conv2: 32ch@c2 -> 64ch@c4 ----
    conv_mfma<32, 64, false><<<ceil_div(nc4, 32), 256, 0, stream>>>(
        A, Wf + off_c2, m3_in, D, nullptr, nc4, nc2, 27);

    // ---- enc2: two BasicBlocks, 64ch on c4 ----
    for (int blk = 0; blk < 2; ++blk) {
        const float* gA = g_e2 + (blk * 2 + 0) * 64, *bA = b_e2 + (blk * 2 + 0) * 64;
        const float* gB = g_e2 + (blk * 2 + 1) * 64, *bB = b_e2 + (blk * 2 + 1) * 64;
        conv_mfma<64, 64, false><<<ceil_div(nc4, 32), 256, 0, stream>>>(
            D, Wf + off_e2[blk * 2 + 0], m4_in, E, stats + slot * 512, nc4, nc4, 27);
        bn_relu_kernel<64><<<ceil_div(nc4 * 64, 256), 256, 0, stream>>>(
            E, stats + slot * 512, gA, bA, nc4);
        ++slot;
        conv_mfma<64, 64, false><<<ceil_div(nc4, 32), 256, 0, stream>>>(
            E, Wf + off_e2[blk * 2 + 1], m4_in, Fb, stats + slot * 512, nc4, nc4, 27);
        if (blk == 0) {
            bn_res_bf16_kernel<64><<<ceil_div(nc4 * 64, 256), 256, 0, stream>>>(
                Fb, D, stats + slot * 512, gB, bB, D, nc4);
        } else {
            bn_res_f32_kernel<64><<<ceil_div(nc4 * 64, 256), 256, 0, stream>>>(
                Fb, D, stats + slot * 512, gB, bB, (float*)d_out, nc4);
        }
        ++slot;
    }
}

// Round 3
// 452.642 us; speedup vs baseline: 3.9846x; 1.0400x over previous
//
#include <hip/hip_runtime.h>
#include <hip/hip_bf16.h>

// ---------------------------------------------------------------------------
// Sparse conv backbone, bf16 MFMA, round 3.
// sparse_conv: out[j] = sum_k fpad[in_map[k][j]] @ W[k]  (identity scatter,
// sentinel gathers zero pad row).  GEMM view: M=n_out, N=COUT, Kdim=K*CIN.
// MFMA 16x16x32 bf16:
//   A-frag: lane holds A[m=lane&15][kd=quad*8+j], j=0..7 (16B contiguous)
//   B-frag: lane holds B[kd=quad*8+j][n=lane&15]  (pre-packed weights)
//   C/D   : col=lane&15, row=quad*4+reg
// R3: one wave owns the full COUT (no redundant A gathers), 4 indep MFMA
// chains per wave, unroll-4 tap loop; single fused prologue kernel.
// ---------------------------------------------------------------------------

typedef float f4 __attribute__((ext_vector_type(4)));
typedef short short8 __attribute__((ext_vector_type(8)));
typedef short short4v __attribute__((ext_vector_type(4)));

#define BN_EPS 1e-5f

static inline int ceil_div(int a, int b) { return (a + b - 1) / b; }

static __device__ inline float btof(short s) {
    unsigned u = ((unsigned)(unsigned short)s) << 16;
    float f;
    __builtin_memcpy(&f, &u, 4);
    return f;
}
static __device__ inline short ftob(float f) {
    __hip_bfloat16 h = __float2bfloat16(f);
    short s;
    __builtin_memcpy(&s, &h, 2);
    return s;
}

// ---------------- fused prologue: pack weights + build x0 + zero stats/pads --
// Wf element e (within segment): j=e&7, lane=(e>>3)&63, rest=e>>9,
// ntile=rest%NT, chunk=rest/NT, kd=chunk*32+(lane>>4)*8+j,
// value = W[kd/CIN][kd%CIN][ntile*16+(lane&15)], 0 if kd/CIN >= K.
struct Seg {
    const float* W;
    long long begin, end;
    int K, CIN, COUT;
};
struct ProArgs {
    Seg s[10];
    const float* geo;
    const float* col;
    __hip_bfloat16* x0;
    int n_vox;
    float* stats;                 // 4096 floats zeroed
    __hip_bfloat16* pads[5];
    int padn[5];
    long long wf_total;
    __hip_bfloat16* Wf;
};

__global__ __launch_bounds__(256) void prologue(ProArgs pa, long long total) {
    long long e = (long long)blockIdx.x * 256 + threadIdx.x;
    if (e >= total) return;
    if (e < pa.wf_total) {
        int si = 0;
#pragma unroll
        for (int i = 0; i < 10; ++i)
            if (e >= pa.s[i].end) si = i + 1;
        const Seg sg = pa.s[si];
        long long r = e - sg.begin;
        int j = (int)(r & 7);
        int lane = (int)((r >> 3) & 63);
        long long rest = r >> 9;
        int NT = sg.COUT >> 4;
        int ntile = (int)(rest % NT);
        int chunk = (int)(rest / NT);
        int kd = chunk * 32 + ((lane >> 4) << 3) + j;
        int koff = kd / sg.CIN;
        int ci = kd % sg.CIN;
        int n = ntile * 16 + (lane & 15);
        float v = (koff < sg.K) ? sg.W[((size_t)koff * sg.CIN + ci) * sg.COUT + n] : 0.f;
        pa.Wf[e] = __float2bfloat16(v);
        return;
    }
    long long r = e - pa.wf_total;
    if (r < pa.n_vox) {
        int row = (int)r;
        pa.x0[row * 4 + 0] = __float2bfloat16(pa.geo[row]);
        pa.x0[row * 4 + 1] = __float2bfloat16(pa.col[row * 3 + 0]);
        pa.x0[row * 4 + 2] = __float2bfloat16(pa.col[row * 3 + 1]);
        pa.x0[row * 4 + 3] = __float2bfloat16(pa.col[row * 3 + 2]);
        return;
    }
    r -= pa.n_vox;
    if (r < 4096) {
        pa.stats[r] = 0.f;
        return;
    }
    r -= 4096;
#pragma unroll
    for (int i = 0; i < 5; ++i) {
        if (r < pa.padn[i]) {
            pa.pads[i][r] = __float2bfloat16(0.f);
            return;
        }
        r -= pa.padn[i];
    }
}

// ---------------- generic MFMA conv ----------------
// One wave owns MT*16 rows x COUT cols (MT*NT indep acc chains).
// Block = 4 waves = 4*MT*16 rows.
template <int CIN, int COUT, int MT, int K>
__global__ __launch_bounds__(256) void conv_mfma(
    const __hip_bfloat16* __restrict__ feat,  // (n_in+1, CIN), pad row zero
    const __hip_bfloat16* __restrict__ Wf,    // packed frag layout
    const int* __restrict__ in_map,           // (K, n_out)
    __hip_bfloat16* __restrict__ out,         // (n_out[+1], COUT)
    float* __restrict__ stats,                // [4][2][COUT] or null
    int n_out, int n_in) {
    constexpr int NT = COUT / 16;
    constexpr int H = CIN / 32;
    const int t = threadIdx.x, w = t >> 6, lane = t & 63;
    const int quad = lane >> 4, ml = lane & 15;
    const int mb = (blockIdx.x * 4 + w) * (MT * 16);

    f4 acc[MT * NT];
#pragma unroll
    for (int i = 0; i < MT * NT; ++i) acc[i] = (f4){0.f, 0.f, 0.f, 0.f};

#pragma unroll 4
    for (int k = 0; k < K; ++k) {
        const int* mk = in_map + (size_t)k * n_out;
        int idx[MT];
#pragma unroll
        for (int mi = 0; mi < MT; ++mi) {
            int m = mb + mi * 16 + ml;
            idx[mi] = (m < n_out) ? mk[m] : n_in;
        }
        short8 bfrag[H * NT];
#pragma unroll
        for (int h = 0; h < H; ++h)
#pragma unroll
            for (int nt = 0; nt < NT; ++nt)
                bfrag[h * NT + nt] = *(const short8*)(
                    Wf + (((size_t)(k * H + h) * NT + nt) * 64 + lane) * 8);
#pragma unroll
        for (int mi = 0; mi < MT; ++mi) {
            const __hip_bfloat16* fp = feat + (size_t)idx[mi] * CIN + quad * 8;
#pragma unroll
            for (int h = 0; h < H; ++h) {
                short8 a = *(const short8*)(fp + h * 32);
#pragma unroll
                for (int nt = 0; nt < NT; ++nt)
                    acc[mi * NT + nt] = __builtin_amdgcn_mfma_f32_16x16x32_bf16(
                        a, bfrag[h * NT + nt], acc[mi * NT + nt], 0, 0, 0);
            }
        }
    }

    float s[NT], s2[NT];
#pragma unroll
    for (int nt = 0; nt < NT; ++nt) { s[nt] = 0.f; s2[nt] = 0.f; }
#pragma unroll
    for (int mi = 0; mi < MT; ++mi) {
#pragma unroll
        for (int i = 0; i < 4; ++i) {
            int row = mb + mi * 16 + quad * 4 + i;
            if (row < n_out) {
#pragma unroll
                for (int nt = 0; nt < NT; ++nt) {
                    float v = acc[mi * NT + nt][i];
                    out[(size_t)row * COUT + nt * 16 + ml] = __float2bfloat16(v);
                    s[nt] += v;
                    s2[nt] += v * v;
                }
            }
        }
    }
    if (stats) {
#pragma unroll
        for (int nt = 0; nt < NT; ++nt) {
            s[nt] += __shfl_xor(s[nt], 16);
            s[nt] += __shfl_xor(s[nt], 32);
            s2[nt] += __shfl_xor(s2[nt], 16);
            s2[nt] += __shfl_xor(s2[nt], 32);
        }
        if (quad == 0) {
            int sub = blockIdx.x & 3;
#pragma unroll
            for (int nt = 0; nt < NT; ++nt) {
                atomicAdd(&stats[(sub * 2 + 0) * COUT + nt * 16 + ml], s[nt]);
                atomicAdd(&stats[(sub * 2 + 1) * COUT + nt * 16 + ml], s2[nt]);
            }
        }
    }
}

// ---------------- stem conv (CIN=4, COUT=32, K=125, relu) ----------------
__global__ __launch_bounds__(256) void stem_mfma(
    const __hip_bfloat16* __restrict__ feat,  // (n_in+1, 4), pad row zero
    const __hip_bfloat16* __restrict__ Wf,    // 16 chunks, NT=2 (padded K)
    const int* __restrict__ in_map,           // (125, n_out)
    __hip_bfloat16* __restrict__ out,         // (n_out[+1], 32)
    int n_out, int n_in) {
    const int t = threadIdx.x, w = t >> 6, lane = t & 63;
    const int quad = lane >> 4, ml = lane & 15;
    const int ntile = w & 1, mgroup = w >> 1;
    const int mb = blockIdx.x * 64 + mgroup * 32;
    const int m0 = mb + ml, m1 = mb + 16 + ml;
    const bool v0 = m0 < n_out, v1 = m1 < n_out;

    f4 acc0 = {0.f, 0.f, 0.f, 0.f};
    f4 acc1 = {0.f, 0.f, 0.f, 0.f};

#pragma unroll 4
    for (int chunk = 0; chunk < 16; ++chunk) {
        int k0 = chunk * 8 + quad * 2;
        int k1 = k0 + 1;
        short8 b = *(const short8*)(Wf + ((size_t)(chunk * 2 + ntile) * 64 + lane) * 8);
        int ia = (v0 && k0 < 125) ? in_map[(size_t)k0 * n_out + m0] : n_in;
        int ib = (v0 && k1 < 125) ? in_map[(size_t)k1 * n_out + m0] : n_in;
        int ic = (v1 && k0 < 125) ? in_map[(size_t)k0 * n_out + m1] : n_in;
        int id = (v1 && k1 < 125) ? in_map[(size_t)k1 * n_out + m1] : n_in;
        short4v pa = *(const short4v*)(feat + (size_t)ia * 4);
        short4v pb = *(const short4v*)(feat + (size_t)ib * 4);
        short4v pc = *(const short4v*)(feat + (size_t)ic * 4);
        short4v pd = *(const short4v*)(feat + (size_t)id * 4);
        short8 a0, a1;
        a0[0] = pa[0]; a0[1] = pa[1]; a0[2] = pa[2]; a0[3] = pa[3];
        a0[4] = pb[0]; a0[5] = pb[1]; a0[6] = pb[2]; a0[7] = pb[3];
        a1[0] = pc[0]; a1[1] = pc[1]; a1[2] = pc[2]; a1[3] = pc[3];
        a1[4] = pd[0]; a1[5] = pd[1]; a1[6] = pd[2]; a1[7] = pd[3];
        acc0 = __builtin_amdgcn_mfma_f32_16x16x32_bf16(a0, b, acc0, 0, 0, 0);
        acc1 = __builtin_amdgcn_mfma_f32_16x16x32_bf16(a1, b, acc1, 0, 0, 0);
    }

    const int col = ntile * 16 + ml;
#pragma unroll
    for (int i = 0; i < 4; ++i) {
        int r0 = mb + quad * 4 + i;
        if (r0 < n_out)
            out[(size_t)r0 * 32 + col] = __float2bfloat16(fmaxf(acc0[i], 0.f));
        int r1 = mb + 16 + quad * 4 + i;
        if (r1 < n_out)
            out[(size_t)r1 * 32 + col] = __float2bfloat16(fmaxf(acc1[i], 0.f));
    }
}

// ---------------- BN apply variants (8-wide, LDS-cached coefficients) -------
template <int C>
__device__ inline void bn_coef(const float* st, const float* g, const float* b,
                               int c, int n, float& sc, float& sh) {
    float rn = 1.f / (float)n;
    float sum = st[c] + st[2 * C + c] + st[4 * C + c] + st[6 * C + c];
    float sq  = st[C + c] + st[3 * C + c] + st[5 * C + c] + st[7 * C + c];
    float mu = sum * rn;
    float inv = rsqrtf(sq * rn - mu * mu + BN_EPS);
    sc = inv * g[c];
    sh = b[c] - mu * sc;
}

template <int C>
__global__ __launch_bounds__(256) void bn_relu8(
    __hip_bfloat16* __restrict__ x, const float* __restrict__ st,
    const float* __restrict__ g, const float* __restrict__ b, int n) {
    __shared__ float sc[C], sh[C];
    const int t = threadIdx.x;
    if (t < C) bn_coef<C>(st, g, b, t, n, sc[t], sh[t]);
    __syncthreads();
    long long i = (long long)blockIdx.x * 256 + t;
    long long tot = (long long)n * (C / 8);
    if (i >= tot) return;
    int c0 = (int)(i % (C / 8)) * 8;
    short8 v = *(const short8*)(x + i * 8);
    short8 o;
#pragma unroll
    for (int j = 0; j < 8; ++j) {
        float f = btof(v[j]) * sc[c0 + j] + sh[c0 + j];
        o[j] = ftob(fmaxf(f, 0.f));
    }
    *(short8*)(x + i * 8) = o;
}

template <int C>
__global__ __launch_bounds__(256) void bn_res8_bf16(
    const __hip_bfloat16* __restrict__ y, const __hip_bfloat16* __restrict__ res,
    const float* __restrict__ st, const float* __restrict__ g,
    const float* __restrict__ b, __hip_bfloat16* __restrict__ out, int n) {
    __shared__ float sc[C], sh[C];
    const int t = threadIdx.x;
    if (t < C) bn_coef<C>(st, g, b, t, n, sc[t], sh[t]);
    __syncthreads();
    long long i = (long long)blockIdx.x * 256 + t;
    long long tot = (long long)n * (C / 8);
    if (i >= tot) return;
    int c0 = (int)(i % (C / 8)) * 8;
    short8 v = *(const short8*)(y + i * 8);
    short8 r = *(const short8*)(res + i * 8);
    short8 o;
#pragma unroll
    for (int j = 0; j < 8; ++j) {
        float f = btof(v[j]) * sc[c0 + j] + sh[c0 + j] + btof(r[j]);
        o[j] = ftob(fmaxf(f, 0.f));
    }
    *(short8*)(out + i * 8) = o;
}

template <int C>
__global__ __launch_bounds__(256) void bn_res8_f32(
    const __hip_bfloat16* __restrict__ y, const __hip_bfloat16* __restrict__ res,
    const float* __restrict__ st, const float* __restrict__ g,
    const float* __restrict__ b, float* __restrict__ out, int n) {
    __shared__ float sc[C], sh[C];
    const int t = threadIdx.x;
    if (t < C) bn_coef<C>(st, g, b, t, n, sc[t], sh[t]);
    __syncthreads();
    long long i = (long long)blockIdx.x * 256 + t;
    long long tot = (long long)n * (C / 8);
    if (i >= tot) return;
    int c0 = (int)(i % (C / 8)) * 8;
    short8 v = *(const short8*)(y + i * 8);
    short8 r = *(const short8*)(res + i * 8);
    f4 o0, o1;
#pragma unroll
    for (int j = 0; j < 8; ++j) {
        float f = btof(v[j]) * sc[c0 + j] + sh[c0 + j] + btof(r[j]);
        f = fmaxf(f, 0.f);
        if (j < 4) o0[j] = f; else o1[j - 4] = f;
    }
    *(f4*)(out + i * 8) = o0;
    *(f4*)(out + i * 8 + 4) = o1;
}

// ---------------------------------------------------------------------------
extern "C" void kernel_launch(void* const* d_in, const int* in_sizes, int n_in_cnt,
                              void* d_out, int out_size, void* d_ws, size_t ws_size,
                              hipStream_t stream) {
    const float* x_geo = (const float*)d_in[0];
    const float* x_col = (const float*)d_in[1];
    const float* w0    = (const float*)d_in[2];   // (125,4,32)
    const float* w_e1  = (const float*)d_in[3];   // (2,2,27,32,32)
    const float* g_e1  = (const float*)d_in[4];
    const float* b_e1  = (const float*)d_in[5];
    const float* w2    = (const float*)d_in[6];   // (27,32,64)
    const float* w_e2  = (const float*)d_in[7];   // (2,2,27,64,64)
    const float* g_e2  = (const float*)d_in[8];
    const float* b_e2  = (const float*)d_in[9];
    const int* m1_in = (const int*)d_in[10];
    const int* m2_in = (const int*)d_in[12];
    const int* m3_in = (const int*)d_in[14];
    const int* m4_in = (const int*)d_in[16];

    const int n_vox = in_sizes[0];
    const int nc2 = in_sizes[10] / 125;
    const int nc4 = in_sizes[14] / 27;
    (void)out_size; (void)ws_size; (void)n_in_cnt;

    // ---- carve workspace (256B-aligned chunks) ----
    char* p = (char*)d_ws;
    auto alloc = [&](size_t bytes) -> char* {
        char* r = p;
        p += (bytes + 255) & ~(size_t)255;
        return r;
    };
    float* stats = (float*)alloc(8 * 512 * sizeof(float));   // 8 slots x [4][2][64]
    __hip_bfloat16* x0 = (__hip_bfloat16*)alloc((size_t)(n_vox + 1) * 4 * 2);
    __hip_bfloat16* A  = (__hip_bfloat16*)alloc((size_t)(nc2 + 1) * 32 * 2);
    __hip_bfloat16* B  = (__hip_bfloat16*)alloc((size_t)(nc2 + 1) * 32 * 2);
    __hip_bfloat16* Cb = (__hip_bfloat16*)alloc((size_t)(nc2 + 1) * 32 * 2);
    __hip_bfloat16* D  = (__hip_bfloat16*)alloc((size_t)(nc4 + 1) * 64 * 2);
    __hip_bfloat16* E  = (__hip_bfloat16*)alloc((size_t)(nc4 + 1) * 64 * 2);
    __hip_bfloat16* Fb = (__hip_bfloat16*)alloc((size_t)(nc4 + 1) * 64 * 2);

    // packed weight segment sizes (elements)
    const long long sz_stem = 16LL * 2 * 512;   // 16 chunks (125*4 padded to 512)
    const long long sz_e1   = 27LL * 2 * 512;
    const long long sz_c2   = 27LL * 4 * 512;
    const long long sz_e2   = 54LL * 4 * 512;
    const long long wf_total = sz_stem + 4 * sz_e1 + sz_c2 + 4 * sz_e2;
    __hip_bfloat16* Wf = (__hip_bfloat16*)alloc((size_t)wf_total * 2);

    long long off_stem = 0;
    long long off_e1[4], off_e2[4];
    long long cur = sz_stem;
    for (int i = 0; i < 4; ++i) { off_e1[i] = cur; cur += sz_e1; }
    long long off_c2 = cur; cur += sz_c2;
    for (int i = 0; i < 4; ++i) { off_e2[i] = cur; cur += sz_e2; }

    // ---- fused prologue: pack + x0 + zero stats/pads ----
    ProArgs pa;
    cur = 0;
    auto seg = [&](int i, const float* W, int K, int CIN, int COUT, long long n) {
        pa.s[i].W = W; pa.s[i].K = K; pa.s[i].CIN = CIN; pa.s[i].COUT = COUT;
        pa.s[i].begin = cur; pa.s[i].end = cur + n; cur += n;
    };
    seg(0, w0, 125, 4, 32, sz_stem);
    for (int i = 0; i < 4; ++i)
        seg(1 + i, w_e1 + (size_t)i * 27 * 32 * 32, 27, 32, 32, sz_e1);
    seg(5, w2, 27, 32, 64, sz_c2);
    for (int i = 0; i < 4; ++i)
        seg(6 + i, w_e2 + (size_t)i * 27 * 64 * 64, 27, 64, 64, sz_e2);
    pa.geo = x_geo; pa.col = x_col; pa.x0 = x0; pa.n_vox = n_vox;
    pa.stats = stats;
    pa.pads[0] = x0 + (size_t)n_vox * 4; pa.padn[0] = 4;
    pa.pads[1] = A + (size_t)nc2 * 32;   pa.padn[1] = 32;
    pa.pads[2] = B + (size_t)nc2 * 32;   pa.padn[2] = 32;
    pa.pads[3] = D + (size_t)nc4 * 64;   pa.padn[3] = 64;
    pa.pads[4] = E + (size_t)nc4 * 64;   pa.padn[4] = 64;
    pa.wf_total = wf_total;
    pa.Wf = Wf;
    long long pro_total = wf_total + n_vox + 4096 + (4 + 32 + 32 + 64 + 64);
    prologue<<<ceil_div((int)pro_total, 256), 256, 0, stream>>>(pa, pro_total);

    // ---- stem ----
    stem_mfma<<<ceil_div(nc2, 64), 256, 0, stream>>>(x0, Wf + off_stem, m1_in, A,
                                                     nc2, n_vox);

    // ---- enc1: two BasicBlocks, 32ch on c2 (wave = 32 rows x 32 cols) ----
    int slot = 0;
    for (int blk = 0; blk < 2; ++blk) {
        const float* gA = g_e1 + (blk * 2 + 0) * 32, *bA = b_e1 + (blk * 2 + 0) * 32;
        const float* gB = g_e1 + (blk * 2 + 1) * 32, *bB = b_e1 + (blk * 2 + 1) * 32;
        conv_mfma<32, 32, 2, 27><<<ceil_div(nc2, 128), 256, 0, stream>>>(
            A, Wf + off_e1[blk * 2 + 0], m2_in, B, stats + slot * 512, nc2, nc2);
        bn_relu8<32><<<ceil_div(nc2 * 4, 256), 256, 0, stream>>>(
            B, stats + slot * 512, gA, bA, nc2);
        ++slot;
        conv_mfma<32, 32, 2, 27><<<ceil_div(nc2, 128), 256, 0, stream>>>(
            B, Wf + off_e1[blk * 2 + 1], m2_in, Cb, stats + slot * 512, nc2, nc2);
        bn_res8_bf16<32><<<ceil_div(nc2 * 4, 256), 256, 0, stream>>>(
            Cb, A, stats + slot * 512, gB, bB, A, nc2);
        ++slot;
    }

    // ---- conv2: 32ch@c2 -> 64ch@c4 (wave = 16 rows x 64 cols) ----
    conv_mfma<32, 64, 1, 27><<<ceil_div(nc4, 64), 256, 0, stream>>>(
        A, Wf + off_c2, m3_in, D, nullptr, nc4, nc2);

    // ---- enc2: two BasicBlocks, 64ch on c4 (wave = 16 rows x 64 cols) ----
    for (int blk = 0; blk < 2; ++blk) {
        const float* gA = g_e2 + (blk * 2 + 0) * 64, *bA = b_e2 + (blk * 2 + 0) * 64;
        const float* gB = g_e2 + (blk * 2 + 1) * 64, *bB = b_e2 + (blk * 2 + 1) * 64;
        conv_mfma<64, 64, 1, 27><<<ceil_div(nc4, 64), 256, 0, stream>>>(
            D, Wf + off_e2[blk * 2 + 0], m4_in, E, stats + slot * 512, nc4, nc4);
        bn_relu8<64><<<ceil_div(nc4 * 8, 256), 256, 0, stream>>>(
            E, stats + slot * 512, gA, bA, nc4);
        ++slot;
        conv_mfma<64, 64, 1, 27><<<ceil_div(nc4, 64), 256, 0, stream>>>(
            E, Wf + off_e2[blk * 2 + 1], m4_in, Fb, stats + slot * 512, nc4, nc4);
        if (blk == 0) {
            bn_res8_bf16<64><<<ceil_div(nc4 * 8, 256), 256, 0, stream>>>(
                Fb, D, stats + slot * 512, gB, bB, D, nc4);
        } else {
            bn_res8_f32<64><<<ceil_div(nc4 * 8, 256), 256, 0, stream>>>(
                Fb, D, stats + slot * 512, gB, bB, (float*)d_out, nc4);
        }
        ++slot;
    }
}

// Round 5
// 360.084 us; speedup vs baseline: 5.0088x; 1.2570x over previous
//
#include <hip/hip_runtime.h>
#include <hip/hip_bf16.h>

// ---------------------------------------------------------------------------
// Sparse conv backbone, bf16 MFMA, round 5: split-K across waves,
// conservative re-implementation (r4 failed; suspects: pragma-unroll on
// runtime-lower-bound loops, LDS buffer aliasing; both removed here).
// sparse_conv: out[j] = sum_k fpad[in_map[k][j]] @ W[k]  (identity scatter,
// sentinel gathers zero pad row).  GEMM view: M=n_out, N=COUT, Kdim=K*CIN.
// MFMA 16x16x32 bf16:
//   A-frag: lane holds A[m=lane&15][kd=quad*8+j], j=0..7 (16B contiguous)
//   B-frag: lane holds B[kd=quad*8+j][n=lane&15]  (pre-packed weights)
//   C/D   : col=lane&15, row=quad*4+reg
// ---------------------------------------------------------------------------

typedef float f4 __attribute__((ext_vector_type(4)));
typedef short short8 __attribute__((ext_vector_type(8)));
typedef short short4v __attribute__((ext_vector_type(4)));

#define BN_EPS 1e-5f

static inline int ceil_div(int a, int b) { return (a + b - 1) / b; }

static __device__ inline float btof(short s) {
    unsigned u = ((unsigned)(unsigned short)s) << 16;
    float f;
    __builtin_memcpy(&f, &u, 4);
    return f;
}
static __device__ inline short ftob(float f) {
    __hip_bfloat16 h = __float2bfloat16(f);
    short s;
    __builtin_memcpy(&s, &h, 2);
    return s;
}

// ---------------- fused prologue: pack weights + build x0 + zero stats/pads --
struct Seg {
    const float* W;
    long long begin, end;
    int K, CIN, COUT;
};
struct ProArgs {
    Seg s[10];
    const float* geo;
    const float* col;
    __hip_bfloat16* x0;
    int n_vox;
    float* stats;                 // 4096 floats zeroed
    __hip_bfloat16* pads[5];
    int padn[5];
    long long wf_total;
    __hip_bfloat16* Wf;
};

__global__ __launch_bounds__(256) void prologue(ProArgs pa, long long total) {
    long long e = (long long)blockIdx.x * 256 + threadIdx.x;
    if (e >= total) return;
    if (e < pa.wf_total) {
        int si = 0;
#pragma unroll
        for (int i = 0; i < 10; ++i)
            if (e >= pa.s[i].end) si = i + 1;
        const Seg sg = pa.s[si];
        long long r = e - sg.begin;
        int j = (int)(r & 7);
        int lane = (int)((r >> 3) & 63);
        long long rest = r >> 9;
        int NT = sg.COUT >> 4;
        int ntile = (int)(rest % NT);
        int chunk = (int)(rest / NT);
        int kd = chunk * 32 + ((lane >> 4) << 3) + j;
        int koff = kd / sg.CIN;
        int ci = kd % sg.CIN;
        int n = ntile * 16 + (lane & 15);
        float v = (koff < sg.K) ? sg.W[((size_t)koff * sg.CIN + ci) * sg.COUT + n] : 0.f;
        pa.Wf[e] = __float2bfloat16(v);
        return;
    }
    long long r = e - pa.wf_total;
    if (r < pa.n_vox) {
        int row = (int)r;
        pa.x0[row * 4 + 0] = __float2bfloat16(pa.geo[row]);
        pa.x0[row * 4 + 1] = __float2bfloat16(pa.col[row * 3 + 0]);
        pa.x0[row * 4 + 2] = __float2bfloat16(pa.col[row * 3 + 1]);
        pa.x0[row * 4 + 3] = __float2bfloat16(pa.col[row * 3 + 2]);
        return;
    }
    r -= pa.n_vox;
    if (r < 4096) {
        pa.stats[r] = 0.f;
        return;
    }
    r -= 4096;
#pragma unroll
    for (int i = 0; i < 5; ++i) {
        if (r < pa.padn[i]) {
            pa.pads[i][r] = __float2bfloat16(0.f);
            return;
        }
        r -= pa.padn[i];
    }
}

// ---------------- split-K MFMA conv (conservative form) ----------------
// Block = 4 waves over R = MT*16 rows; wave w handles taps k = 4*kk + w.
// LDS reduce across waves; separate LDS buffer for stats reduction.
template <int CIN, int COUT, int MT, int K>
__global__ __launch_bounds__(256) void conv_splitk(
    const __hip_bfloat16* __restrict__ feat,  // (n_in+1, CIN), pad row zero
    const __hip_bfloat16* __restrict__ Wf,    // packed frag layout
    const int* __restrict__ in_map,           // (K, n_out)
    __hip_bfloat16* __restrict__ out,         // (n_out[+1], COUT)
    float* __restrict__ stats,                // [4][2][COUT] or null
    int n_out, int n_in) {
    constexpr int NT = COUT / 16;
    constexpr int H = CIN / 32;
    constexpr int R = MT * 16;
    constexpr int KPW = (K + 3) / 4;
    const int t = threadIdx.x, w = t >> 6, lane = t & 63;
    const int quad = lane >> 4, ml = lane & 15;
    const int mb = blockIdx.x * R;

    __shared__ float red[4][R][COUT];
    __shared__ float sred[2][256];

    f4 acc[MT * NT];
#pragma unroll
    for (int i = 0; i < MT * NT; ++i) acc[i] = (f4){0.f, 0.f, 0.f, 0.f};

    for (int kk = 0; kk < KPW; ++kk) {
        const int k = kk * 4 + w;
        if (k < K) {
            const int* mk = in_map + (size_t)k * n_out;
            int idx[MT];
#pragma unroll
            for (int mi = 0; mi < MT; ++mi) {
                int m = mb + mi * 16 + ml;
                idx[mi] = (m < n_out) ? mk[m] : n_in;
            }
            short8 bfrag[H * NT];
#pragma unroll
            for (int h = 0; h < H; ++h)
#pragma unroll
                for (int nt = 0; nt < NT; ++nt)
                    bfrag[h * NT + nt] = *(const short8*)(
                        Wf + (((size_t)(k * H + h) * NT + nt) * 64 + lane) * 8);
#pragma unroll
            for (int mi = 0; mi < MT; ++mi) {
                const __hip_bfloat16* fp = feat + (size_t)idx[mi] * CIN + quad * 8;
#pragma unroll
                for (int h = 0; h < H; ++h) {
                    short8 a = *(const short8*)(fp + h * 32);
#pragma unroll
                    for (int nt = 0; nt < NT; ++nt)
                        acc[mi * NT + nt] = __builtin_amdgcn_mfma_f32_16x16x32_bf16(
                            a, bfrag[h * NT + nt], acc[mi * NT + nt], 0, 0, 0);
                }
            }
        }
    }

#pragma unroll
    for (int mi = 0; mi < MT; ++mi)
#pragma unroll
        for (int nt = 0; nt < NT; ++nt)
#pragma unroll
            for (int i = 0; i < 4; ++i)
                red[w][mi * 16 + quad * 4 + i][nt * 16 + ml] = acc[mi * NT + nt][i];
    __syncthreads();

    // combine: thread owns channel col = t%COUT, rows rg + i*RSTEP
    constexpr int E = (R * COUT) / 256;
    constexpr int RSTEP = 256 / COUT;
    const int col = t % COUT;
    const int rg = t / COUT;
    float s = 0.f, s2 = 0.f;
#pragma unroll
    for (int i = 0; i < E; ++i) {
        int r = rg + i * RSTEP;
        float v = red[0][r][col] + red[1][r][col] + red[2][r][col] + red[3][r][col];
        s += v;
        s2 += v * v;
        int grow = mb + r;
        if (grow < n_out) out[(size_t)grow * COUT + col] = __float2bfloat16(v);
    }

    if (stats) {
        sred[0][t] = s;
        sred[1][t] = s2;
        __syncthreads();
        if (t < 2 * COUT) {
            int c = t % COUT;
            int which = t / COUT;   // 0 = sum, 1 = sumsq
            float v = 0.f;
#pragma unroll
            for (int j = 0; j < RSTEP; ++j) v += sred[which][j * COUT + c];
            atomicAdd(&stats[((blockIdx.x & 3) * 2 + which) * COUT + c], v);
        }
    }
}

// ---------------- stem conv (CIN=4, COUT=32, K=125, relu) — r3 proven -------
__global__ __launch_bounds__(256) void stem_mfma(
    const __hip_bfloat16* __restrict__ feat,  // (n_in+1, 4), pad row zero
    const __hip_bfloat16* __restrict__ Wf,    // 16 chunks, NT=2 (padded K)
    const int* __restrict__ in_map,           // (125, n_out)
    __hip_bfloat16* __restrict__ out,         // (n_out[+1], 32)
    int n_out, int n_in) {
    const int t = threadIdx.x, w = t >> 6, lane = t & 63;
    const int quad = lane >> 4, ml = lane & 15;
    const int ntile = w & 1, mgroup = w >> 1;
    const int mb = blockIdx.x * 64 + mgroup * 32;
    const int m0 = mb + ml, m1 = mb + 16 + ml;
    const bool v0 = m0 < n_out, v1 = m1 < n_out;

    f4 acc0 = {0.f, 0.f, 0.f, 0.f};
    f4 acc1 = {0.f, 0.f, 0.f, 0.f};

#pragma unroll 4
    for (int chunk = 0; chunk < 16; ++chunk) {
        int k0 = chunk * 8 + quad * 2;
        int k1 = k0 + 1;
        short8 b = *(const short8*)(Wf + ((size_t)(chunk * 2 + ntile) * 64 + lane) * 8);
        int ia = (v0 && k0 < 125) ? in_map[(size_t)k0 * n_out + m0] : n_in;
        int ib = (v0 && k1 < 125) ? in_map[(size_t)k1 * n_out + m0] : n_in;
        int ic = (v1 && k0 < 125) ? in_map[(size_t)k0 * n_out + m1] : n_in;
        int id = (v1 && k1 < 125) ? in_map[(size_t)k1 * n_out + m1] : n_in;
        short4v pa = *(const short4v*)(feat + (size_t)ia * 4);
        short4v pb = *(const short4v*)(feat + (size_t)ib * 4);
        short4v pc = *(const short4v*)(feat + (size_t)ic * 4);
        short4v pd = *(const short4v*)(feat + (size_t)id * 4);
        short8 a0, a1;
        a0[0] = pa[0]; a0[1] = pa[1]; a0[2] = pa[2]; a0[3] = pa[3];
        a0[4] = pb[0]; a0[5] = pb[1]; a0[6] = pb[2]; a0[7] = pb[3];
        a1[0] = pc[0]; a1[1] = pc[1]; a1[2] = pc[2]; a1[3] = pc[3];
        a1[4] = pd[0]; a1[5] = pd[1]; a1[6] = pd[2]; a1[7] = pd[3];
        acc0 = __builtin_amdgcn_mfma_f32_16x16x32_bf16(a0, b, acc0, 0, 0, 0);
        acc1 = __builtin_amdgcn_mfma_f32_16x16x32_bf16(a1, b, acc1, 0, 0, 0);
    }

    const int col = ntile * 16 + ml;
#pragma unroll
    for (int i = 0; i < 4; ++i) {
        int r0 = mb + quad * 4 + i;
        if (r0 < n_out)
            out[(size_t)r0 * 32 + col] = __float2bfloat16(fmaxf(acc0[i], 0.f));
        int r1 = mb + 16 + quad * 4 + i;
        if (r1 < n_out)
            out[(size_t)r1 * 32 + col] = __float2bfloat16(fmaxf(acc1[i], 0.f));
    }
}

// ---------------- BN apply variants (8-wide, LDS-cached coefficients) -------
template <int C>
__device__ inline void bn_coef(const float* st, const float* g, const float* b,
                               int c, int n, float& sc, float& sh) {
    float rn = 1.f / (float)n;
    float sum = st[c] + st[2 * C + c] + st[4 * C + c] + st[6 * C + c];
    float sq  = st[C + c] + st[3 * C + c] + st[5 * C + c] + st[7 * C + c];
    float mu = sum * rn;
    float inv = rsqrtf(sq * rn - mu * mu + BN_EPS);
    sc = inv * g[c];
    sh = b[c] - mu * sc;
}

template <int C>
__global__ __launch_bounds__(256) void bn_relu8(
    __hip_bfloat16* __restrict__ x, const float* __restrict__ st,
    const float* __restrict__ g, const float* __restrict__ b, int n) {
    __shared__ float sc[C], sh[C];
    const int t = threadIdx.x;
    if (t < C) bn_coef<C>(st, g, b, t, n, sc[t], sh[t]);
    __syncthreads();
    long long i = (long long)blockIdx.x * 256 + t;
    long long tot = (long long)n * (C / 8);
    if (i >= tot) return;
    int c0 = (int)(i % (C / 8)) * 8;
    short8 v = *(const short8*)(x + i * 8);
    short8 o;
#pragma unroll
    for (int j = 0; j < 8; ++j) {
        float f = btof(v[j]) * sc[c0 + j] + sh[c0 + j];
        o[j] = ftob(fmaxf(f, 0.f));
    }
    *(short8*)(x + i * 8) = o;
}

template <int C>
__global__ __launch_bounds__(256) void bn_res8_bf16(
    const __hip_bfloat16* __restrict__ y, const __hip_bfloat16* __restrict__ res,
    const float* __restrict__ st, const float* __restrict__ g,
    const float* __restrict__ b, __hip_bfloat16* __restrict__ out, int n) {
    __shared__ float sc[C], sh[C];
    const int t = threadIdx.x;
    if (t < C) bn_coef<C>(st, g, b, t, n, sc[t], sh[t]);
    __syncthreads();
    long long i = (long long)blockIdx.x * 256 + t;
    long long tot = (long long)n * (C / 8);
    if (i >= tot) return;
    int c0 = (int)(i % (C / 8)) * 8;
    short8 v = *(const short8*)(y + i * 8);
    short8 r = *(const short8*)(res + i * 8);
    short8 o;
#pragma unroll
    for (int j = 0; j < 8; ++j) {
        float f = btof(v[j]) * sc[c0 + j] + sh[c0 + j] + btof(r[j]);
        o[j] = ftob(fmaxf(f, 0.f));
    }
    *(short8*)(out + i * 8) = o;
}

template <int C>
__global__ __launch_bounds__(256) void bn_res8_f32(
    const __hip_bfloat16* __restrict__ y, const __hip_bfloat16* __restrict__ res,
    const float* __restrict__ st, const float* __restrict__ g,
    const float* __restrict__ b, float* __restrict__ out, int n) {
    __shared__ float sc[C], sh[C];
    const int t = threadIdx.x;
    if (t < C) bn_coef<C>(st, g, b, t, n, sc[t], sh[t]);
    __syncthreads();
    long long i = (long long)blockIdx.x * 256 + t;
    long long tot = (long long)n * (C / 8);
    if (i >= tot) return;
    int c0 = (int)(i % (C / 8)) * 8;
    short8 v = *(const short8*)(y + i * 8);
    short8 r = *(const short8*)(res + i * 8);
    f4 o0, o1;
#pragma unroll
    for (int j = 0; j < 8; ++j) {
        float f = btof(v[j]) * sc[c0 + j] + sh[c0 + j] + btof(r[j]);
        f = fmaxf(f, 0.f);
        if (j < 4) o0[j] = f; else o1[j - 4] = f;
    }
    *(f4*)(out + i * 8) = o0;
    *(f4*)(out + i * 8 + 4) = o1;
}

// ---------------------------------------------------------------------------
extern "C" void kernel_launch(void* const* d_in, const int* in_sizes, int n_in_cnt,
                              void* d_out, int out_size, void* d_ws, size_t ws_size,
                              hipStream_t stream) {
    const float* x_geo = (const float*)d_in[0];
    const float* x_col = (const float*)d_in[1];
    const float* w0    = (const float*)d_in[2];   // (125,4,32)
    const float* w_e1  = (const float*)d_in[3];   // (2,2,27,32,32)
    const float* g_e1  = (const float*)d_in[4];
    const float* b_e1  = (const float*)d_in[5];
    const float* w2    = (const float*)d_in[6];   // (27,32,64)
    const float* w_e2  = (const float*)d_in[7];   // (2,2,27,64,64)
    const float* g_e2  = (const float*)d_in[8];
    const float* b_e2  = (const float*)d_in[9];
    const int* m1_in = (const int*)d_in[10];
    const int* m2_in = (const int*)d_in[12];
    const int* m3_in = (const int*)d_in[14];
    const int* m4_in = (const int*)d_in[16];

    const int n_vox = in_sizes[0];
    const int nc2 = in_sizes[10] / 125;
    const int nc4 = in_sizes[14] / 27;
    (void)out_size; (void)ws_size; (void)n_in_cnt;

    // ---- carve workspace (256B-aligned chunks) ----
    char* p = (char*)d_ws;
    auto alloc = [&](size_t bytes) -> char* {
        char* r = p;
        p += (bytes + 255) & ~(size_t)255;
        return r;
    };
    float* stats = (float*)alloc(8 * 512 * sizeof(float));   // 8 slots x [4][2][64]
    __hip_bfloat16* x0 = (__hip_bfloat16*)alloc((size_t)(n_vox + 1) * 4 * 2);
    __hip_bfloat16* A  = (__hip_bfloat16*)alloc((size_t)(nc2 + 1) * 32 * 2);
    __hip_bfloat16* B  = (__hip_bfloat16*)alloc((size_t)(nc2 + 1) * 32 * 2);
    __hip_bfloat16* Cb = (__hip_bfloat16*)alloc((size_t)(nc2 + 1) * 32 * 2);
    __hip_bfloat16* D  = (__hip_bfloat16*)alloc((size_t)(nc4 + 1) * 64 * 2);
    __hip_bfloat16* E  = (__hip_bfloat16*)alloc((size_t)(nc4 + 1) * 64 * 2);
    __hip_bfloat16* Fb = (__hip_bfloat16*)alloc((size_t)(nc4 + 1) * 64 * 2);

    // packed weight segment sizes (elements)
    const long long sz_stem = 16LL * 2 * 512;   // 16 chunks (125*4 padded to 512)
    const long long sz_e1   = 27LL * 2 * 512;
    const long long sz_c2   = 27LL * 4 * 512;
    const long long sz_e2   = 54LL * 4 * 512;
    const long long wf_total = sz_stem + 4 * sz_e1 + sz_c2 + 4 * sz_e2;
    __hip_bfloat16* Wf = (__hip_bfloat16*)alloc((size_t)wf_total * 2);

    long long off_stem = 0;
    long long off_e1[4], off_e2[4];
    long long cur = sz_stem;
    for (int i = 0; i < 4; ++i) { off_e1[i] = cur; cur += sz_e1; }
    long long off_c2 = cur; cur += sz_c2;
    for (int i = 0; i < 4; ++i) { off_e2[i] = cur; cur += sz_e2; }

    // ---- fused prologue: pack + x0 + zero stats/pads ----
    ProArgs pa;
    cur = 0;
    auto seg = [&](int i, const float* W, int K, int CIN, int COUT, long long n) {
        pa.s[i].W = W; pa.s[i].K = K; pa.s[i].CIN = CIN; pa.s[i].COUT = COUT;
        pa.s[i].begin = cur; pa.s[i].end = cur + n; cur += n;
    };
    seg(0, w0, 125, 4, 32, sz_stem);
    for (int i = 0; i < 4; ++i)
        seg(1 + i, w_e1 + (size_t)i * 27 * 32 * 32, 27, 32, 32, sz_e1);
    seg(5, w2, 27, 32, 64, sz_c2);
    for (int i = 0; i < 4; ++i)
        seg(6 + i, w_e2 + (size_t)i * 27 * 64 * 64, 27, 64, 64, sz_e2);
    pa.geo = x_geo; pa.col = x_col; pa.x0 = x0; pa.n_vox = n_vox;
    pa.stats = stats;
    pa.pads[0] = x0 + (size_t)n_vox * 4; pa.padn[0] = 4;
    pa.pads[1] = A + (size_t)nc2 * 32;   pa.padn[1] = 32;
    pa.pads[2] = B + (size_t)nc2 * 32;   pa.padn[2] = 32;
    pa.pads[3] = D + (size_t)nc4 * 64;   pa.padn[3] = 64;
    pa.pads[4] = E + (size_t)nc4 * 64;   pa.padn[4] = 64;
    pa.wf_total = wf_total;
    pa.Wf = Wf;
    long long pro_total = wf_total + n_vox + 4096 + (4 + 32 + 32 + 64 + 64);
    prologue<<<ceil_div((int)pro_total, 256), 256, 0, stream>>>(pa, pro_total);

    // ---- stem (r3 proven version, 64 rows/block) ----
    stem_mfma<<<ceil_div(nc2, 64), 256, 0, stream>>>(x0, Wf + off_stem, m1_in, A,
                                                     nc2, n_vox);

    // ---- enc1: two BasicBlocks, 32ch on c2 (32 rows/block, split-K 4) ----
    int slot = 0;
    for (int blk = 0; blk < 2; ++blk) {
        const float* gA = g_e1 + (blk * 2 + 0) * 32, *bA = b_e1 + (blk * 2 + 0) * 32;
        const float* gB = g_e1 + (blk * 2 + 1) * 32, *bB = b_e1 + (blk * 2 + 1) * 32;
        conv_splitk<32, 32, 2, 27><<<ceil_div(nc2, 32), 256, 0, stream>>>(
            A, Wf + off_e1[blk * 2 + 0], m2_in, B, stats + slot * 512, nc2, nc2);
        bn_relu8<32><<<ceil_div(nc2 * 4, 256), 256, 0, stream>>>(
            B, stats + slot * 512, gA, bA, nc2);
        ++slot;
        conv_splitk<32, 32, 2, 27><<<ceil_div(nc2, 32), 256, 0, stream>>>(
            B, Wf + off_e1[blk * 2 + 1], m2_in, Cb, stats + slot * 512, nc2, nc2);
        bn_res8_bf16<32><<<ceil_div(nc2 * 4, 256), 256, 0, stream>>>(
            Cb, A, stats + slot * 512, gB, bB, A, nc2);
        ++slot;
    }

    // ---- conv2: 32ch@c2 -> 64ch@c4 (16 rows/block, split-K 4) ----
    conv_splitk<32, 64, 1, 27><<<ceil_div(nc4, 16), 256, 0, stream>>>(
        A, Wf + off_c2, m3_in, D, nullptr, nc4, nc2);

    // ---- enc2: two BasicBlocks, 64ch on c4 (16 rows/block, split-K 4) ----
    for (int blk = 0; blk < 2; ++blk) {
        const float* gA = g_e2 + (blk * 2 + 0) * 64, *bA = b_e2 + (blk * 2 + 0) * 64;
        const float* gB = g_e2 + (blk * 2 + 1) * 64, *bB = b_e2 + (blk * 2 + 1) * 64;
        conv_splitk<64, 64, 1, 27><<<ceil_div(nc4, 16), 256, 0, stream>>>(
            D, Wf + off_e2[blk * 2 + 0], m4_in, E, stats + slot * 512, nc4, nc4);
        bn_relu8<64><<<ceil_div(nc4 * 8, 256), 256, 0, stream>>>(
            E, stats + slot * 512, gA, bA, nc4);
        ++slot;
        conv_splitk<64, 64, 1, 27><<<ceil_div(nc4, 16), 256, 0, stream>>>(
            E, Wf + off_e2[blk * 2 + 1], m4_in, Fb, stats + slot * 512, nc4, nc4);
        if (blk == 0) {
            bn_res8_bf16<64><<<ceil_div(nc4 * 8, 256), 256, 0, stream>>>(
                Fb, D, stats + slot * 512, gB, bB, D, nc4);
        } else {
            bn_res8_f32<64><<<ceil_div(nc4 * 8, 256), 256, 0, stream>>>(
                Fb, D, stats + slot * 512, gB, bB, (float*)d_out, nc4);
        }
        ++slot;
    }
}

// Round 6
// 341.649 us; speedup vs baseline: 5.2791x; 1.0540x over previous
//
#include <hip/hip_runtime.h>
#include <hip/hip_bf16.h>

// ---------------------------------------------------------------------------
// Sparse conv backbone, bf16 MFMA, round 6.
// sparse_conv: out[j] = sum_k fpad[in_map[k][j]] @ W[k]  (identity scatter,
// sentinel gathers zero pad row).  GEMM view: M=n_out, N=COUT, Kdim=K*CIN.
// MFMA 16x16x32 bf16:
//   A-frag: lane holds A[m=lane&15][kd=quad*8+j], j=0..7 (16B contiguous)
//   B-frag: lane holds B[kd=quad*8+j][n=lane&15]  (pre-packed weights)
//   C/D   : col=lane&15, row=quad*4+reg
// R6 vs R5: (a) taps padded to KPW*4=28 with zero weights -> tap loop is
// branch-free with constant trip count, fully unrolled (loads of all taps
// can overlap; r5's in-loop `if (k<K)` serialized the gather chains);
// (b) bn_relu fused into the consuming conv's gather (sentinel rows zeroed
// AFTER bn, matching reference's y-space padding); bn_res kernels remain.
// ---------------------------------------------------------------------------

typedef float f4 __attribute__((ext_vector_type(4)));
typedef short short8 __attribute__((ext_vector_type(8)));
typedef short short4v __attribute__((ext_vector_type(4)));

#define BN_EPS 1e-5f

static inline int ceil_div(int a, int b) { return (a + b - 1) / b; }

static __device__ inline float btof(short s) {
    unsigned u = ((unsigned)(unsigned short)s) << 16;
    float f;
    __builtin_memcpy(&f, &u, 4);
    return f;
}
static __device__ inline short ftob(float f) {
    __hip_bfloat16 h = __float2bfloat16(f);
    short s;
    __builtin_memcpy(&s, &h, 2);
    return s;
}

// ---------------- fused prologue: pack weights + build x0 + zero stats/pads --
struct Seg {
    const float* W;
    long long begin, end;
    int K, CIN, COUT;
};
struct ProArgs {
    Seg s[10];
    const float* geo;
    const float* col;
    __hip_bfloat16* x0;
    int n_vox;
    float* stats;                 // 4096 floats zeroed
    __hip_bfloat16* pads[5];
    int padn[5];
    long long wf_total;
    __hip_bfloat16* Wf;
};

__global__ __launch_bounds__(256) void prologue(ProArgs pa, long long total) {
    long long e = (long long)blockIdx.x * 256 + threadIdx.x;
    if (e >= total) return;
    if (e < pa.wf_total) {
        int si = 0;
#pragma unroll
        for (int i = 0; i < 10; ++i)
            if (e >= pa.s[i].end) si = i + 1;
        const Seg sg = pa.s[si];
        long long r = e - sg.begin;
        int j = (int)(r & 7);
        int lane = (int)((r >> 3) & 63);
        long long rest = r >> 9;
        int NT = sg.COUT >> 4;
        int ntile = (int)(rest % NT);
        int chunk = (int)(rest / NT);
        int kd = chunk * 32 + ((lane >> 4) << 3) + j;
        int koff = kd / sg.CIN;
        int ci = kd % sg.CIN;
        int n = ntile * 16 + (lane & 15);
        float v = (koff < sg.K) ? sg.W[((size_t)koff * sg.CIN + ci) * sg.COUT + n] : 0.f;
        pa.Wf[e] = __float2bfloat16(v);
        return;
    }
    long long r = e - pa.wf_total;
    if (r < pa.n_vox) {
        int row = (int)r;
        pa.x0[row * 4 + 0] = __float2bfloat16(pa.geo[row]);
        pa.x0[row * 4 + 1] = __float2bfloat16(pa.col[row * 3 + 0]);
        pa.x0[row * 4 + 2] = __float2bfloat16(pa.col[row * 3 + 1]);
        pa.x0[row * 4 + 3] = __float2bfloat16(pa.col[row * 3 + 2]);
        return;
    }
    r -= pa.n_vox;
    if (r < 4096) {
        pa.stats[r] = 0.f;
        return;
    }
    r -= 4096;
#pragma unroll
    for (int i = 0; i < 5; ++i) {
        if (r < pa.padn[i]) {
            pa.pads[i][r] = __float2bfloat16(0.f);
            return;
        }
        r -= pa.padn[i];
    }
}

// ---------------- BN coefficient helper ----------------
template <int C>
__device__ inline void bn_coef(const float* st, const float* g, const float* b,
                               int c, int n, float& sc, float& sh) {
    float rn = 1.f / (float)n;
    float sum = st[c] + st[2 * C + c] + st[4 * C + c] + st[6 * C + c];
    float sq  = st[C + c] + st[3 * C + c] + st[5 * C + c] + st[7 * C + c];
    float mu = sum * rn;
    float inv = rsqrtf(sq * rn - mu * mu + BN_EPS);
    sc = inv * g[c];
    sh = b[c] - mu * sc;
}

// ---------------- split-K MFMA conv ----------------
// Block = 4 waves over R = MT*16 rows; wave w handles taps k = 4*kk + w,
// kk = 0..KPW-1 (taps padded to KPW*4 with zero weights -> branch-free).
// Optional fused input-BN+ReLU on gathered rows (BNF): rows are the RAW
// output of the producing conv; sentinel rows forced to 0 after BN.
template <int CIN, int COUT, int MT, int K, bool BNF>
__global__ __launch_bounds__(256) void conv_splitk(
    const __hip_bfloat16* __restrict__ feat,  // (n_in+1, CIN)
    const __hip_bfloat16* __restrict__ Wf,    // packed frag layout, KPW*4 taps
    const int* __restrict__ in_map,           // (K, n_out)
    __hip_bfloat16* __restrict__ out,         // (n_out[+1], COUT)
    float* __restrict__ stats,                // [4][2][COUT] or null
    const float* __restrict__ in_stats,       // producer stats (BNF)
    const float* __restrict__ in_g,
    const float* __restrict__ in_b,
    int n_out, int n_in) {
    constexpr int NT = COUT / 16;
    constexpr int H = CIN / 32;
    constexpr int R = MT * 16;
    constexpr int KPW = (K + 3) / 4;
    const int t = threadIdx.x, w = t >> 6, lane = t & 63;
    const int quad = lane >> 4, ml = lane & 15;
    const int mb = blockIdx.x * R;

    __shared__ float red[4][R][COUT];
    __shared__ float sred[2][256];
    __shared__ float isc[CIN], ish[CIN];

    if (BNF) {
        if (t < CIN) {
            float sc, sh;
            bn_coef<CIN>(in_stats, in_g, in_b, t, n_in, sc, sh);
            isc[t] = sc;
            ish[t] = sh;
        }
        __syncthreads();
    }
    float scr[H][8], shr[H][8];
    if (BNF) {
#pragma unroll
        for (int h = 0; h < H; ++h)
#pragma unroll
            for (int j = 0; j < 8; ++j) {
                int ch = h * 32 + quad * 8 + j;
                scr[h][j] = isc[ch];
                shr[h][j] = ish[ch];
            }
    }

    f4 acc[MT * NT];
#pragma unroll
    for (int i = 0; i < MT * NT; ++i) acc[i] = (f4){0.f, 0.f, 0.f, 0.f};

#pragma unroll
    for (int kk = 0; kk < KPW; ++kk) {
        const int k = kk * 4 + w;             // 0 .. KPW*4-1 (weights zero k>=K)
        const int krow = (k < K) ? k : 0;     // branchless row select
        const int* mk = in_map + (size_t)krow * n_out;
        int idx[MT];
#pragma unroll
        for (int mi = 0; mi < MT; ++mi) {
            int m = mb + mi * 16 + ml;
            idx[mi] = (m < n_out) ? mk[m] : n_in;
        }
        short8 bfrag[H * NT];
#pragma unroll
        for (int h = 0; h < H; ++h)
#pragma unroll
            for (int nt = 0; nt < NT; ++nt)
                bfrag[h * NT + nt] = *(const short8*)(
                    Wf + (((size_t)(k * H + h) * NT + nt) * 64 + lane) * 8);
#pragma unroll
        for (int mi = 0; mi < MT; ++mi) {
            const __hip_bfloat16* fp = feat + (size_t)idx[mi] * CIN + quad * 8;
            const bool sent = (idx[mi] == n_in);
#pragma unroll
            for (int h = 0; h < H; ++h) {
                short8 a = *(const short8*)(fp + h * 32);
                if (BNF) {
#pragma unroll
                    for (int j = 0; j < 8; ++j) {
                        float f = btof(a[j]) * scr[h][j] + shr[h][j];
                        f = fmaxf(f, 0.f);
                        a[j] = sent ? (short)0 : ftob(f);
                    }
                }
#pragma unroll
                for (int nt = 0; nt < NT; ++nt)
                    acc[mi * NT + nt] = __builtin_amdgcn_mfma_f32_16x16x32_bf16(
                        a, bfrag[h * NT + nt], acc[mi * NT + nt], 0, 0, 0);
            }
        }
    }

#pragma unroll
    for (int mi = 0; mi < MT; ++mi)
#pragma unroll
        for (int nt = 0; nt < NT; ++nt)
#pragma unroll
            for (int i = 0; i < 4; ++i)
                red[w][mi * 16 + quad * 4 + i][nt * 16 + ml] = acc[mi * NT + nt][i];
    __syncthreads();

    constexpr int E = (R * COUT) / 256;
    constexpr int RSTEP = 256 / COUT;
    const int col = t % COUT;
    const int rg = t / COUT;
    float s = 0.f, s2 = 0.f;
#pragma unroll
    for (int i = 0; i < E; ++i) {
        int r = rg + i * RSTEP;
        float v = red[0][r][col] + red[1][r][col] + red[2][r][col] + red[3][r][col];
        s += v;
        s2 += v * v;
        int grow = mb + r;
        if (grow < n_out) out[(size_t)grow * COUT + col] = __float2bfloat16(v);
    }

    if (stats) {
        sred[0][t] = s;
        sred[1][t] = s2;
        __syncthreads();
        if (t < 2 * COUT) {
            int c = t % COUT;
            int which = t / COUT;   // 0 = sum, 1 = sumsq
            float v = 0.f;
#pragma unroll
            for (int j = 0; j < RSTEP; ++j) v += sred[which][j * COUT + c];
            atomicAdd(&stats[((blockIdx.x & 3) * 2 + which) * COUT + c], v);
        }
    }
}

// ---------------- stem conv (CIN=4, COUT=32, K=125 padded to 128, relu) -----
__global__ __launch_bounds__(256) void stem_mfma(
    const __hip_bfloat16* __restrict__ feat,  // (n_in+1, 4), pad row zero
    const __hip_bfloat16* __restrict__ Wf,    // 16 chunks, NT=2 (zero k>=125)
    const int* __restrict__ in_map,           // (125, n_out)
    __hip_bfloat16* __restrict__ out,         // (n_out[+1], 32)
    int n_out, int n_in) {
    const int t = threadIdx.x, w = t >> 6, lane = t & 63;
    const int quad = lane >> 4, ml = lane & 15;
    const int ntile = w & 1, mgroup = w >> 1;
    const int mb = blockIdx.x * 64 + mgroup * 32;
    const int m0 = mb + ml, m1 = mb + 16 + ml;
    const bool v0 = m0 < n_out, v1 = m1 < n_out;

    f4 acc0 = {0.f, 0.f, 0.f, 0.f};
    f4 acc1 = {0.f, 0.f, 0.f, 0.f};

#pragma unroll 4
    for (int chunk = 0; chunk < 16; ++chunk) {
        int k0 = chunk * 8 + quad * 2;
        int k1 = k0 + 1;
        int k0c = (k0 < 125) ? k0 : 0;   // weights zero for k>=125
        int k1c = (k1 < 125) ? k1 : 0;
        short8 b = *(const short8*)(Wf + ((size_t)(chunk * 2 + ntile) * 64 + lane) * 8);
        int ia = v0 ? in_map[(size_t)k0c * n_out + m0] : n_in;
        int ib = v0 ? in_map[(size_t)k1c * n_out + m0] : n_in;
        int ic = v1 ? in_map[(size_t)k0c * n_out + m1] : n_in;
        int id = v1 ? in_map[(size_t)k1c * n_out + m1] : n_in;
        short4v pa = *(const short4v*)(feat + (size_t)ia * 4);
        short4v pb = *(const short4v*)(feat + (size_t)ib * 4);
        short4v pc = *(const short4v*)(feat + (size_t)ic * 4);
        short4v pd = *(const short4v*)(feat + (size_t)id * 4);
        short8 a0, a1;
        a0[0] = pa[0]; a0[1] = pa[1]; a0[2] = pa[2]; a0[3] = pa[3];
        a0[4] = pb[0]; a0[5] = pb[1]; a0[6] = pb[2]; a0[7] = pb[3];
        a1[0] = pc[0]; a1[1] = pc[1]; a1[2] = pc[2]; a1[3] = pc[3];
        a1[4] = pd[0]; a1[5] = pd[1]; a1[6] = pd[2]; a1[7] = pd[3];
        acc0 = __builtin_amdgcn_mfma_f32_16x16x32_bf16(a0, b, acc0, 0, 0, 0);
        acc1 = __builtin_amdgcn_mfma_f32_16x16x32_bf16(a1, b, acc1, 0, 0, 0);
    }

    const int col = ntile * 16 + ml;
#pragma unroll
    for (int i = 0; i < 4; ++i) {
        int r0 = mb + quad * 4 + i;
        if (r0 < n_out)
            out[(size_t)r0 * 32 + col] = __float2bfloat16(fmaxf(acc0[i], 0.f));
        int r1 = mb + 16 + quad * 4 + i;
        if (r1 < n_out)
            out[(size_t)r1 * 32 + col] = __float2bfloat16(fmaxf(acc1[i], 0.f));
    }
}

// ---------------- BN residual apply (8-wide, LDS-cached coefficients) -------
template <int C>
__global__ __launch_bounds__(256) void bn_res8_bf16(
    const __hip_bfloat16* __restrict__ y, const __hip_bfloat16* __restrict__ res,
    const float* __restrict__ st, const float* __restrict__ g,
    const float* __restrict__ b, __hip_bfloat16* __restrict__ out, int n) {
    __shared__ float sc[C], sh[C];
    const int t = threadIdx.x;
    if (t < C) bn_coef<C>(st, g, b, t, n, sc[t], sh[t]);
    __syncthreads();
    long long i = (long long)blockIdx.x * 256 + t;
    long long tot = (long long)n * (C / 8);
    if (i >= tot) return;
    int c0 = (int)(i % (C / 8)) * 8;
    short8 v = *(const short8*)(y + i * 8);
    short8 r = *(const short8*)(res + i * 8);
    short8 o;
#pragma unroll
    for (int j = 0; j < 8; ++j) {
        float f = btof(v[j]) * sc[c0 + j] + sh[c0 + j] + btof(r[j]);
        o[j] = ftob(fmaxf(f, 0.f));
    }
    *(short8*)(out + i * 8) = o;
}

template <int C>
__global__ __launch_bounds__(256) void bn_res8_f32(
    const __hip_bfloat16* __restrict__ y, const __hip_bfloat16* __restrict__ res,
    const float* __restrict__ st, const float* __restrict__ g,
    const float* __restrict__ b, float* __restrict__ out, int n) {
    __shared__ float sc[C], sh[C];
    const int t = threadIdx.x;
    if (t < C) bn_coef<C>(st, g, b, t, n, sc[t], sh[t]);
    __syncthreads();
    long long i = (long long)blockIdx.x * 256 + t;
    long long tot = (long long)n * (C / 8);
    if (i >= tot) return;
    int c0 = (int)(i % (C / 8)) * 8;
    short8 v = *(const short8*)(y + i * 8);
    short8 r = *(const short8*)(res + i * 8);
    f4 o0, o1;
#pragma unroll
    for (int j = 0; j < 8; ++j) {
        float f = btof(v[j]) * sc[c0 + j] + sh[c0 + j] + btof(r[j]);
        f = fmaxf(f, 0.f);
        if (j < 4) o0[j] = f; else o1[j - 4] = f;
    }
    *(f4*)(out + i * 8) = o0;
    *(f4*)(out + i * 8 + 4) = o1;
}

// ---------------------------------------------------------------------------
extern "C" void kernel_launch(void* const* d_in, const int* in_sizes, int n_in_cnt,
                              void* d_out, int out_size, void* d_ws, size_t ws_size,
                              hipStream_t stream) {
    const float* x_geo = (const float*)d_in[0];
    const float* x_col = (const float*)d_in[1];
    const float* w0    = (const float*)d_in[2];   // (125,4,32)
    const float* w_e1  = (const float*)d_in[3];   // (2,2,27,32,32)
    const float* g_e1  = (const float*)d_in[4];
    const float* b_e1  = (const float*)d_in[5];
    const float* w2    = (const float*)d_in[6];   // (27,32,64)
    const float* w_e2  = (const float*)d_in[7];   // (2,2,27,64,64)
    const float* g_e2  = (const float*)d_in[8];
    const float* b_e2  = (const float*)d_in[9];
    const int* m1_in = (const int*)d_in[10];
    const int* m2_in = (const int*)d_in[12];
    const int* m3_in = (const int*)d_in[14];
    const int* m4_in = (const int*)d_in[16];

    const int n_vox = in_sizes[0];
    const int nc2 = in_sizes[10] / 125;
    const int nc4 = in_sizes[14] / 27;
    (void)out_size; (void)ws_size; (void)n_in_cnt;

    // ---- carve workspace (256B-aligned chunks) ----
    char* p = (char*)d_ws;
    auto alloc = [&](size_t bytes) -> char* {
        char* r = p;
        p += (bytes + 255) & ~(size_t)255;
        return r;
    };
    float* stats = (float*)alloc(8 * 512 * sizeof(float));   // 8 slots x [4][2][64]
    __hip_bfloat16* x0 = (__hip_bfloat16*)alloc((size_t)(n_vox + 1) * 4 * 2);
    __hip_bfloat16* A  = (__hip_bfloat16*)alloc((size_t)(nc2 + 1) * 32 * 2);
    __hip_bfloat16* B  = (__hip_bfloat16*)alloc((size_t)(nc2 + 1) * 32 * 2);
    __hip_bfloat16* Cb = (__hip_bfloat16*)alloc((size_t)(nc2 + 1) * 32 * 2);
    __hip_bfloat16* D  = (__hip_bfloat16*)alloc((size_t)(nc4 + 1) * 64 * 2);
    __hip_bfloat16* E  = (__hip_bfloat16*)alloc((size_t)(nc4 + 1) * 64 * 2);
    __hip_bfloat16* Fb = (__hip_bfloat16*)alloc((size_t)(nc4 + 1) * 64 * 2);

    // packed weight segment sizes (elements); taps padded to 28 for convs
    const long long sz_stem = 16LL * 2 * 512;   // 128 taps (125 real)
    const long long sz_e1   = 28LL * 2 * 512;   // 28 taps x H=1, NT=2
    const long long sz_c2   = 28LL * 4 * 512;   // 28 taps x H=1, NT=4
    const long long sz_e2   = 56LL * 4 * 512;   // 28 taps x H=2, NT=4
    const long long wf_total = sz_stem + 4 * sz_e1 + sz_c2 + 4 * sz_e2;
    __hip_bfloat16* Wf = (__hip_bfloat16*)alloc((size_t)wf_total * 2);

    long long off_stem = 0;
    long long off_e1[4], off_e2[4];
    long long cur = sz_stem;
    for (int i = 0; i < 4; ++i) { off_e1[i] = cur; cur += sz_e1; }
    long long off_c2 = cur; cur += sz_c2;
    for (int i = 0; i < 4; ++i) { off_e2[i] = cur; cur += sz_e2; }

    // ---- fused prologue: pack + x0 + zero stats/pads ----
    ProArgs pa;
    cur = 0;
    auto seg = [&](int i, const float* W, int K, int CIN, int COUT, long long n) {
        pa.s[i].W = W; pa.s[i].K = K; pa.s[i].CIN = CIN; pa.s[i].COUT = COUT;
        pa.s[i].begin = cur; pa.s[i].end = cur + n; cur += n;
    };
    seg(0, w0, 125, 4, 32, sz_stem);
    for (int i = 0; i < 4; ++i)
        seg(1 + i, w_e1 + (size_t)i * 27 * 32 * 32, 27, 32, 32, sz_e1);
    seg(5, w2, 27, 32, 64, sz_c2);
    for (int i = 0; i < 4; ++i)
        seg(6 + i, w_e2 + (size_t)i * 27 * 64 * 64, 27, 64, 64, sz_e2);
    pa.geo = x_geo; pa.col = x_col; pa.x0 = x0; pa.n_vox = n_vox;
    pa.stats = stats;
    pa.pads[0] = x0 + (size_t)n_vox * 4; pa.padn[0] = 4;
    pa.pads[1] = A + (size_t)nc2 * 32;   pa.padn[1] = 32;
    pa.pads[2] = B + (size_t)nc2 * 32;   pa.padn[2] = 32;
    pa.pads[3] = D + (size_t)nc4 * 64;   pa.padn[3] = 64;
    pa.pads[4] = E + (size_t)nc4 * 64;   pa.padn[4] = 64;
    pa.wf_total = wf_total;
    pa.Wf = Wf;
    long long pro_total = wf_total + n_vox + 4096 + (4 + 32 + 32 + 64 + 64);
    prologue<<<ceil_div((int)pro_total, 256), 256, 0, stream>>>(pa, pro_total);

    // ---- stem (64 rows/block) ----
    stem_mfma<<<ceil_div(nc2, 64), 256, 0, stream>>>(x0, Wf + off_stem, m1_in, A,
                                                     nc2, n_vox);

    // ---- enc1: two BasicBlocks, 32ch on c2 (32 rows/block, split-K 4) ----
    int slot = 0;
    for (int blk = 0; blk < 2; ++blk) {
        const float* gA = g_e1 + (blk * 2 + 0) * 32, *bA = b_e1 + (blk * 2 + 0) * 32;
        const float* gB = g_e1 + (blk * 2 + 1) * 32, *bB = b_e1 + (blk * 2 + 1) * 32;
        // conv1: plain gather of finalized A -> raw B + stats[slot]
        conv_splitk<32, 32, 2, 27, false><<<ceil_div(nc2, 32), 256, 0, stream>>>(
            A, Wf + off_e1[blk * 2 + 0], m2_in, B, stats + slot * 512,
            nullptr, nullptr, nullptr, nc2, nc2);
        // conv2: gather raw B with fused bn_relu(stats[slot]) -> raw Cb + stats
        conv_splitk<32, 32, 2, 27, true><<<ceil_div(nc2, 32), 256, 0, stream>>>(
            B, Wf + off_e1[blk * 2 + 1], m2_in, Cb, stats + (slot + 1) * 512,
            stats + slot * 512, gA, bA, nc2, nc2);
        bn_res8_bf16<32><<<ceil_div(nc2 * 4, 256), 256, 0, stream>>>(
            Cb, A, stats + (slot + 1) * 512, gB, bB, A, nc2);
        slot += 2;
    }

    // ---- conv2: 32ch@c2 -> 64ch@c4 (16 rows/block, split-K 4) ----
    conv_splitk<32, 64, 1, 27, false><<<ceil_div(nc4, 16), 256, 0, stream>>>(
        A, Wf + off_c2, m3_in, D, nullptr,
        nullptr, nullptr, nullptr, nc4, nc2);

    // ---- enc2: two BasicBlocks, 64ch on c4 (16 rows/block, split-K 4) ----
    for (int blk = 0; blk < 2; ++blk) {
        const float* gA = g_e2 + (blk * 2 + 0) * 64, *bA = b_e2 + (blk * 2 + 0) * 64;
        const float* gB = g_e2 + (blk * 2 + 1) * 64, *bB = b_e2 + (blk * 2 + 1) * 64;
        conv_splitk<64, 64, 1, 27, false><<<ceil_div(nc4, 16), 256, 0, stream>>>(
            D, Wf + off_e2[blk * 2 + 0], m4_in, E, stats + slot * 512,
            nullptr, nullptr, nullptr, nc4, nc4);
        conv_splitk<64, 64, 1, 27, true><<<ceil_div(nc4, 16), 256, 0, stream>>>(
            E, Wf + off_e2[blk * 2 + 1], m4_in, Fb, stats + (slot + 1) * 512,
            stats + slot * 512, gA, bA, nc4, nc4);
        if (blk == 0) {
            bn_res8_bf16<64><<<ceil_div(nc4 * 8, 256), 256, 0, stream>>>(
                Fb, D, stats + (slot + 1) * 512, gB, bB, D, nc4);
        } else {
            bn_res8_f32<64><<<ceil_div(nc4 * 8, 256), 256, 0, stream>>>(
                Fb, D, stats + (slot + 1) * 512, gB, bB, (float*)d_out, nc4);
        }
        slot += 2;
    }
}